// Round 11
// baseline (394.535 us; speedup 1.0000x reference)
//
#include <hip/hip_runtime.h>
#include <cstdint>
#include <cstddef>

// Problem constants (from reference)
#define NN 50000
#define NE 800000
#define FIN 256
#define HD 128
#define NEG_SLOPE 0.2f

// CSR-build binning parameters
#define NBK 196          // buckets of 256 nodes: ceil(50000/256)
#define NCH 98           // edge chunks
#define CHUNK 8192       // edges per chunk (98*8192 >= 800000)

typedef short s16x8 __attribute__((ext_vector_type(8)));   // 8 bf16 (4 VGPRs)
typedef float f32x4 __attribute__((ext_vector_type(4)));   // MFMA accumulator

__device__ inline ushort f2bf(float f) {                   // fp32 -> bf16 RTN-even
    uint32_t u = __float_as_uint(f);
    u += 0x7FFFu + ((u >> 16) & 1u);
    return (ushort)(u >> 16);
}
__device__ inline float bf2f(ushort h) {
    return __uint_as_float(((uint32_t)h) << 16);
}

// ------------------------------------------------------------- CSR build
// bucket = dst >> 8. No global atomics anywhere.

__global__ __launch_bounds__(1024) void k_bhist(const int* __restrict__ dst,
                                                int* __restrict__ bhist) {
    __shared__ int hist[NBK];
    const int tid = threadIdx.x, blk = blockIdx.x;
    if (tid < NBK) hist[tid] = 0;
    __syncthreads();
    const int e0 = blk * CHUNK;
    #pragma unroll
    for (int u = 0; u < CHUNK / 1024; ++u) {
        int e = e0 + u * 1024 + tid;
        if (e < NE) atomicAdd(&hist[dst[e] >> 8], 1);
    }
    __syncthreads();
    if (tid < NBK) bhist[blk * NBK + tid] = hist[tid];
}

__global__ __launch_bounds__(256) void k_bscan(int* __restrict__ bhist,
                                               int* __restrict__ bbeg,
                                               int* __restrict__ row_ptr) {
    __shared__ int wsum[4];
    const int tid = threadIdx.x;
    int tot = 0;
    if (tid < NBK) {
        for (int c = 0; c < NCH; ++c) {           // coalesced across tid
            int t = bhist[c * NBK + tid];
            bhist[c * NBK + tid] = tot;           // per-bucket chunk prefix
            tot += t;
        }
    }
    const int lane = tid & 63, wid = tid >> 6;
    int x = tot;
    #pragma unroll
    for (int o = 1; o < 64; o <<= 1) {
        int t = __shfl_up(x, o);
        if (lane >= o) x += t;
    }
    if (lane == 63) wsum[wid] = x;
    __syncthreads();
    int wo = 0;
    for (int k = 0; k < wid; ++k) wo += wsum[k];
    const int excl = x - tot + wo;                // bucket start offset
    if (tid < NBK) bbeg[tid] = excl;
    if (tid == 0) { bbeg[NBK] = NE; row_ptr[NN] = NE; }
    __syncthreads();
    if (tid < NBK)
        for (int c = 0; c < NCH; ++c) bhist[c * NBK + tid] += excl;
}

__global__ __launch_bounds__(1024) void k_binscatter(const int* __restrict__ src,
                                                     const int* __restrict__ dst,
                                                     const float* __restrict__ ew,
                                                     const int* __restrict__ bhist,
                                                     uint2* __restrict__ epk) {
    __shared__ int base[NBK];
    __shared__ int lcur[NBK];
    const int tid = threadIdx.x, blk = blockIdx.x;
    if (tid < NBK) { base[tid] = bhist[blk * NBK + tid]; lcur[tid] = 0; }
    __syncthreads();
    const int e0 = blk * CHUNK;
    #pragma unroll
    for (int u = 0; u < CHUNK / 1024; ++u) {
        int e = e0 + u * 1024 + tid;
        if (e < NE) {
            int d = dst[e];
            int s = src[e];
            float w = ew[e];
            int b = d >> 8;
            int pos = base[b] + atomicAdd(&lcur[b], 1);   // LDS atomic only
            epk[pos] = make_uint2((uint32_t)s | ((uint32_t)(d & 255) << 16),
                                  __float_as_uint(w));
        }
    }
}

__global__ __launch_bounds__(256) void k_build(const uint2* __restrict__ epk,
                                               const int* __restrict__ bbeg,
                                               int* __restrict__ row_ptr,
                                               int* __restrict__ col,
                                               float* __restrict__ wsrt) {
    __shared__ int cnt[256];
    __shared__ int cur[256];
    __shared__ int wsum[4];
    const int tid = threadIdx.x, b = blockIdx.x;
    const int n0 = b << 8;
    const int ebeg = bbeg[b], eend = bbeg[b + 1];
    cnt[tid] = 0;
    __syncthreads();
    for (int e = ebeg + tid; e < eend; e += 256)
        atomicAdd(&cnt[(epk[e].x >> 16) & 255], 1);
    __syncthreads();
    const int v = cnt[tid];
    const int lane = tid & 63, wid = tid >> 6;
    int x = v;
    #pragma unroll
    for (int o = 1; o < 64; o <<= 1) {
        int t = __shfl_up(x, o);
        if (lane >= o) x += t;
    }
    if (lane == 63) wsum[wid] = x;
    __syncthreads();
    int wo = 0;
    for (int k = 0; k < wid; ++k) wo += wsum[k];
    const int excl = ebeg + x - v + wo;           // node segment start
    if (n0 + tid < NN) row_ptr[n0 + tid] = excl;
    cur[tid] = excl;
    __syncthreads();
    for (int e = ebeg + tid; e < eend; e += 256) {
        uint2 p = epk[e];
        int dl = (p.x >> 16) & 255;
        int pos = atomicAdd(&cur[dl], 1);
        col[pos]  = (int)(p.x & 0xFFFFu);
        wsrt[pos] = __uint_as_float(p.y);
    }
}

// -------------------------------------------- weight transpose + bf16 split
// W [K][HD] fp32 row-major -> Th/Tl [HD][K] bf16 (hi + residual-lo)

__global__ void k_split(const float* __restrict__ W, ushort* __restrict__ Th,
                        ushort* __restrict__ Tl, int K) {
    int idx = blockIdx.x * blockDim.x + threadIdx.x;   // = n*K + k
    if (idx >= K * HD) return;
    int n = idx / K, k = idx - n * K;
    float f = W[(size_t)k * HD + n];
    ushort hi = f2bf(f);
    Th[idx] = hi;
    Tl[idx] = f2bf(f - bf2f(hi));
}

// ----------------------------------------------------- MFMA split-bf16 GEMM
// C[M][128] = A[M][K] @ B[K][128] (+bias), 16x16x32 bf16 MFMA,
// D = Ahi*Bhi + Ahi*Blo + Alo*Bhi  (~fp32 accuracy).
// BM=64 (grid 782), BK=64 (32 KB LDS), 4 waves x 16 rows; single-stage
// swizzled B tile; barrier-free inner loop.
// bf16 output (Cb) is written as 4 XCD-local quarter tables [4][NN][32].

template <int K, bool ATT>
__global__ __launch_bounds__(256) void k_gemm_mfma(
    const float*  __restrict__ A,
    const ushort* __restrict__ Bh,     // [HD][K]
    const ushort* __restrict__ Bl,     // [HD][K]
    const float*  __restrict__ bias,   // null if none
    float*        __restrict__ Cf,     // fp32 out (null if unused)
    ushort*       __restrict__ Cb,     // bf16 quarter-tables (null if unused)
    const float*  __restrict__ att_s, const float* __restrict__ att_d,
    float* __restrict__ as_, float* __restrict__ ad_,
    int M)
{
    constexpr int BK = 64;                        // K-elems per LDS tile
    constexpr int NT = K / BK;                    // 2 or 4 tiles
    __shared__ ushort Bs[16384];                  // 32 KB: hi [0..8191], lo +8192

    const int tid  = threadIdx.x;
    const int lane = tid & 63;
    const int wid  = tid >> 6;                    // 0..3
    const int fl   = lane & 15;                   // A row / B col within frag
    const int fg   = lane >> 4;                   // k-group (8 elems)
    const int rowBase = blockIdx.x * 64 + wid * 16;

    f32x4 acc[8] = {};

    for (int t = 0; t < NT; ++t) {
        if (t) __syncthreads();                   // all waves done with tile t-1
        #pragma unroll
        for (int u = 0; u < 4; ++u) {
            const int id  = u * 256 + tid;
            const int bcol = id >> 3, c = id & 7;
            const size_t g = (size_t)bcol * K + t * BK + c * 8;
            const int lidx = bcol * 64 + ((c ^ (bcol & 7)) << 3);
            *reinterpret_cast<uint4*>(&Bs[lidx]) =
                *reinterpret_cast<const uint4*>(Bh + g);
            *reinterpret_cast<uint4*>(&Bs[8192 + lidx]) =
                *reinterpret_cast<const uint4*>(Bl + g);
        }
        __syncthreads();

        #pragma unroll
        for (int kt = 0; kt < 2; ++kt) {
            int r = rowBase + fl;
            if (r >= M) r = M - 1;                // harmless clamp (stores guarded)
            const float* ap = A + (size_t)r * K + t * BK + kt * 32 + fg * 8;
            float4 t0 = *reinterpret_cast<const float4*>(ap);
            float4 t1 = *reinterpret_cast<const float4*>(ap + 4);
            float v[8] = {t0.x, t0.y, t0.z, t0.w, t1.x, t1.y, t1.z, t1.w};
            s16x8 a_h, a_l;
            #pragma unroll
            for (int u = 0; u < 8; ++u) {
                ushort h0 = f2bf(v[u]);
                a_h[u] = (short)h0;
                a_l[u] = (short)f2bf(v[u] - bf2f(h0));
            }
            #pragma unroll
            for (int ct = 0; ct < 8; ++ct) {
                const int colI = ct * 16 + fl;
                const int lidx = colI * 64 + (((kt * 4 + fg) ^ (colI & 7)) << 3);
                s16x8 b_h = *reinterpret_cast<const s16x8*>(&Bs[lidx]);
                s16x8 b_l = *reinterpret_cast<const s16x8*>(&Bs[8192 + lidx]);
                acc[ct] = __builtin_amdgcn_mfma_f32_16x16x32_bf16(a_h, b_h, acc[ct], 0, 0, 0);
                acc[ct] = __builtin_amdgcn_mfma_f32_16x16x32_bf16(a_h, b_l, acc[ct], 0, 0, 0);
                acc[ct] = __builtin_amdgcn_mfma_f32_16x16x32_bf16(a_l, b_h, acc[ct], 0, 0, 0);
            }
        }
    }

    // ---- epilogue: C/D layout col = ct*16 + fl, row = rowBase + fg*4 + reg ----
    float bval[8];
    #pragma unroll
    for (int ct = 0; ct < 8; ++ct) bval[ct] = bias ? bias[ct * 16 + fl] : 0.f;
    float asv[8], adv[8];
    if (ATT) {
        #pragma unroll
        for (int ct = 0; ct < 8; ++ct) {
            asv[ct] = att_s[ct * 16 + fl];
            adv[ct] = att_d[ct * 16 + fl];
        }
    }

    const int rbase = rowBase + fg * 4;
    #pragma unroll
    for (int r = 0; r < 4; ++r) {
        const int row = rbase + r;
        const bool ok = row < M;
        float sv = 0.f, dv = 0.f;
        #pragma unroll
        for (int ct = 0; ct < 8; ++ct) {
            float val = acc[ct][r] + bval[ct];
            if (ATT) { sv = fmaf(val, asv[ct], sv); dv = fmaf(val, adv[ct], dv); }
            if (ok) {
                if (Cf) Cf[(size_t)row * HD + ct * 16 + fl] = val;
                if (Cb)                                    // quarter table: q = ct>>1
                    Cb[((size_t)(ct >> 1) * NN + row) * 32 + (ct & 1) * 16 + fl] = f2bf(val);
            }
        }
        if (ATT) {
            #pragma unroll
            for (int o = 1; o < 16; o <<= 1) {        // reduce within 16-lane group
                sv += __shfl_xor(sv, o);
                dv += __shfl_xor(dv, o);
            }
            if (fl == 0 && ok) { as_[row] = sv; ad_[row] = dv; }
        }
    }
}

// ---------------------------------------------- fused softmax-aggregation
// XCD-feature-partitioned: group g = blockIdx & 3 processes feature quarter
// [g*32, g*32+32) from its own 3.2 MB table hpq[g][NN][32] (fits one L2).
// With the %8 round-robin block->XCD mapping, group g lands on XCDs {g, g+4}
// only, so each XCD's L2 caches exactly one quarter table -> FETCH_SIZE
// drops ~2x (the measured ~2.2 TB/s fill-path was the binding limit).
// One wave per (node, group). Lane owns 4 features (uint2); 8 lanes cover a
// quarter-row; eighth = lane>>3 processes 8 edges per load instruction.
// Weights computed in-wave (no max pass; softmax shift-invariant, l<=80).
// mode: 0 = h += agg (no out); 1 = out = max(h_old, h_old+agg), h += agg;
// 2 = out = max(out, agg + b).

__global__ __launch_bounds__(256) void k_agg(const ushort* __restrict__ hpq,
                                             float* __restrict__ h,
                                             const float* __restrict__ as_,
                                             const float* __restrict__ ad_,
                                             const int* __restrict__ row_ptr,
                                             const int* __restrict__ col,
                                             const float* __restrict__ wsrt,
                                             const float* __restrict__ bias,
                                             float* __restrict__ out, int mode) {
    const int g    = blockIdx.x & 3;            // feature quarter / XCD pair
    const int wid  = threadIdx.x >> 6;
    const int lane = threadIdx.x & 63;
    const int d    = (blockIdx.x >> 2) * 4 + wid;
    if (d >= NN) return;
    const int beg = row_ptr[d], end = row_ptr[d + 1];
    const float adv = ad_[d];
    const int eighth = lane >> 3;               // which of 8 concurrent edges
    const int hl     = lane & 7;                // features [g*32+hl*4, +4)
    const ushort* tq = hpq + (size_t)g * NN * 32;

    float a0 = 0.f, a1 = 0.f, a2 = 0.f, a3 = 0.f, dloc = 0.f;
    for (int base = beg; base < end; base += 64) {
        const int n = min(64, end - base);
        int s = 0; float w = 0.f;
        if (lane < n) {
            s = col[base + lane];
            float l = as_[s] + adv;
            l = (l >= 0.f) ? l : NEG_SLOPE * l;
            l = fminf(l, 80.f);                 // overflow guard (no max pass)
            w = __expf(l) * wsrt[base + lane];
        }
        dloc += w;

        int i = 0;
        for (; i + 31 < n; i += 32) {           // 4 loads = 32 edges in flight
            float wv[4]; int sv[4]; uint2 pv[4];
            #pragma unroll
            for (int j = 0; j < 4; ++j) {
                const int idx = i + 8 * j + eighth;
                wv[j] = __shfl(w, idx);
                sv[j] = __shfl(s, idx);
            }
            #pragma unroll
            for (int j = 0; j < 4; ++j)
                pv[j] = *reinterpret_cast<const uint2*>(tq + (size_t)sv[j] * 32 + hl * 4);
            #pragma unroll
            for (int j = 0; j < 4; ++j) {
                a0 = fmaf(wv[j], bf2f((ushort)pv[j].x),         a0);
                a1 = fmaf(wv[j], bf2f((ushort)(pv[j].x >> 16)), a1);
                a2 = fmaf(wv[j], bf2f((ushort)pv[j].y),         a2);
                a3 = fmaf(wv[j], bf2f((ushort)(pv[j].y >> 16)), a3);
            }
        }
        for (; i + 7 < n; i += 8) {             // full 8-edge steps
            const int idx = i + eighth;
            float wj = __shfl(w, idx);
            int   sj = __shfl(s, idx);
            uint2 pv = *reinterpret_cast<const uint2*>(tq + (size_t)sj * 32 + hl * 4);
            a0 = fmaf(wj, bf2f((ushort)pv.x),         a0);
            a1 = fmaf(wj, bf2f((ushort)(pv.x >> 16)), a1);
            a2 = fmaf(wj, bf2f((ushort)pv.y),         a2);
            a3 = fmaf(wj, bf2f((ushort)(pv.y >> 16)), a3);
        }
        if (i < n) {                            // tail < 8 edges (masked)
            const int e = i + eighth;
            const bool ok = e < n;
            const int idx = ok ? e : i;
            float wj = __shfl(w, idx);
            int   sj = __shfl(s, idx);
            if (!ok) wj = 0.f;
            uint2 pv = *reinterpret_cast<const uint2*>(tq + (size_t)sj * 32 + hl * 4);
            a0 = fmaf(wj, bf2f((ushort)pv.x),         a0);
            a1 = fmaf(wj, bf2f((ushort)(pv.x >> 16)), a1);
            a2 = fmaf(wj, bf2f((ushort)pv.y),         a2);
            a3 = fmaf(wj, bf2f((ushort)(pv.y >> 16)), a3);
        }
    }
    #pragma unroll
    for (int o = 32; o > 0; o >>= 1) dloc += __shfl_xor(dloc, o);
    #pragma unroll
    for (int o = 32; o >= 8; o >>= 1) {
        a0 += __shfl_xor(a0, o); a1 += __shfl_xor(a1, o);
        a2 += __shfl_xor(a2, o); a3 += __shfl_xor(a3, o);
    }

    if (eighth != 0) return;                    // lanes 0-7 do the stores
    const float inv = 1.f / (dloc + 1e-16f);
    const int f0 = g * 32 + hl * 4;
    float4 r;
    r.x = a0 * inv + bias[f0 + 0];
    r.y = a1 * inv + bias[f0 + 1];
    r.z = a2 * inv + bias[f0 + 2];
    r.w = a3 * inv + bias[f0 + 3];

    float4* outp = reinterpret_cast<float4*>(out + (size_t)d * HD + f0);
    float4* hp4  = reinterpret_cast<float4*>(h   + (size_t)d * HD + f0);
    if (mode == 2) {
        float4 o = *outp;
        o.x = fmaxf(o.x, r.x); o.y = fmaxf(o.y, r.y);
        o.z = fmaxf(o.z, r.z); o.w = fmaxf(o.w, r.w);
        *outp = o;
    } else {
        float4 hv = *hp4;
        float4 hn;
        hn.x = hv.x + r.x; hn.y = hv.y + r.y;
        hn.z = hv.z + r.z; hn.w = hv.w + r.w;
        *hp4 = hn;
        if (mode == 1) {                        // out = max(h1, h2), no out read
            float4 mx;
            mx.x = fmaxf(hv.x, hn.x); mx.y = fmaxf(hv.y, hn.y);
            mx.z = fmaxf(hv.z, hn.z); mx.w = fmaxf(hv.w, hn.w);
            *outp = mx;
        }
    }
}

// ---------------------------------------------------------------- launch

extern "C" void kernel_launch(void* const* d_in, const int* in_sizes, int n_in,
                              void* d_out, int out_size, void* d_ws, size_t ws_size,
                              hipStream_t stream) {
    const float* x        = (const float*)d_in[0];          // [NN][FIN]
    const int*   ei       = (const int*)d_in[1];            // [2][NE]
    const float* ew       = (const float*)d_in[2];          // [NE]
    /* d_in[3] = numNode scalar = NN */
    const float* Wlin     = (const float*)d_in[4];          // [FIN][HD]
    const float* blin     = (const float*)d_in[5];          // [HD]
    const float* Wc       = (const float*)d_in[6];          // [3][HD][HD]
    const float* att_src  = (const float*)d_in[7];          // [3][HD]
    const float* att_dst  = (const float*)d_in[8];          // [3][HD]
    const float* bias_c   = (const float*)d_in[9];          // [3][HD]
    float* out = (float*)d_out;                              // [NN][HD]

    const int* src = ei;
    const int* dst = ei + NE;

    // workspace layout (16B-aligned blocks, ~52 MB)
    char* w = (char*)d_ws;
    float*  h       = (float*)w;   w += (size_t)NN * HD * 4;
    ushort* hpq     = (ushort*)w;  w += (size_t)NN * HD * 2;   // [4][NN][32] bf16
    float*  as_     = (float*)w;   w += (size_t)NN * 4;
    float*  ad_     = (float*)w;   w += (size_t)NN * 4;
    int*    row_ptr = (int*)w;     w += (size_t)(NN + 4) * 4;
    int*    col     = (int*)w;     w += (size_t)NE * 4;
    float*  wsrt    = (float*)w;   w += (size_t)NE * 4;
    uint2*  epk     = (uint2*)w;   w += (size_t)NE * 8;
    int*    bhist   = (int*)w;     w += (size_t)NCH * NBK * 4;
    int*    bbeg    = (int*)w;     w += (size_t)(NBK + 4) * 4;
    ushort* WTh     = (ushort*)w;  w += (size_t)(HD * FIN + 3 * HD * HD) * 2;
    ushort* WTl     = (ushort*)w;  w += (size_t)(HD * FIN + 3 * HD * HD) * 2;
    ushort* WlinTh = WTh,            *WlinTl = WTl;
    ushort* WcTh   = WTh + HD * FIN, *WcTl   = WTl + HD * FIN;

    const int TB = 256;
    const int nblk_agg = (NN / 4) * 4;               // 50000: 12500 node-blocks x 4 groups
    const int nblk_g = (NN + 63) / 64;               // 782 (64 rows per block)

    // ---- weight transpose + split (tiny) ----
    k_split<<<(HD * FIN + TB - 1) / TB, TB, 0, stream>>>(Wlin, WlinTh, WlinTl, FIN);
    for (int l = 0; l < 3; ++l)
        k_split<<<(HD * HD + TB - 1) / TB, TB, 0, stream>>>(
            Wc + (size_t)l * HD * HD, WcTh + (size_t)l * HD * HD,
            WcTl + (size_t)l * HD * HD, HD);

    // ---- CSR build (atomic-reservation-free binning) ----
    k_bhist<<<NCH, 1024, 0, stream>>>(dst, bhist);
    k_bscan<<<1, 256, 0, stream>>>(bhist, bbeg, row_ptr);
    k_binscatter<<<NCH, 1024, 0, stream>>>(src, dst, ew, bhist, epk);
    k_build<<<NBK, 256, 0, stream>>>(epk, bbeg, row_ptr, col, wsrt);

    // ---- input projection: h = x @ Wlin + blin (fp32 out) ----
    k_gemm_mfma<FIN, false><<<nblk_g, TB, 0, stream>>>(
        x, WlinTh, WlinTl, blin, h, nullptr, nullptr, nullptr, nullptr, nullptr, NN);

    // ---- 3 GAT layers ----
    for (int layer = 0; layer < 3; ++layer) {
        k_gemm_mfma<HD, true><<<nblk_g, TB, 0, stream>>>(
            h, WcTh + (size_t)layer * HD * HD, WcTl + (size_t)layer * HD * HD,
            nullptr, nullptr, hpq,
            att_src + layer * HD, att_dst + layer * HD, as_, ad_, NN);
        int mode = (layer == 0) ? 0 : (layer == 2 ? 2 : 1);
        k_agg<<<nblk_agg, TB, 0, stream>>>(hpq, h, as_, ad_, row_ptr, col, wsrt,
                                           bias_c + layer * HD, out, mode);
    }
}

// Round 12
// 236.706 us; speedup vs baseline: 1.6668x; 1.6668x over previous
//
#include <hip/hip_runtime.h>
#include <cstdint>
#include <cstddef>

// Problem constants (from reference)
#define NN 50000
#define NE 800000
#define FIN 256
#define HD 128
#define NEG_SLOPE 0.2f

// CSR-build binning parameters
#define NBK 196          // buckets of 256 nodes: ceil(50000/256)
#define NCH 98           // edge chunks
#define CHUNK 8192       // edges per chunk (98*8192 >= 800000)

typedef short s16x8 __attribute__((ext_vector_type(8)));   // 8 bf16 (4 VGPRs)
typedef float f32x4 __attribute__((ext_vector_type(4)));   // MFMA accumulator

__device__ inline ushort f2bf(float f) {                   // fp32 -> bf16 RTN-even
    uint32_t u = __float_as_uint(f);
    u += 0x7FFFu + ((u >> 16) & 1u);
    return (ushort)(u >> 16);
}
__device__ inline float bf2f(ushort h) {
    return __uint_as_float(((uint32_t)h) << 16);
}

// ------------------------------------------------------------- CSR build
// bucket = dst >> 8. No global atomics anywhere.

__global__ __launch_bounds__(1024) void k_bhist(const int* __restrict__ dst,
                                                int* __restrict__ bhist) {
    __shared__ int hist[NBK];
    const int tid = threadIdx.x, blk = blockIdx.x;
    if (tid < NBK) hist[tid] = 0;
    __syncthreads();
    const int e0 = blk * CHUNK;
    #pragma unroll
    for (int u = 0; u < CHUNK / 1024; ++u) {
        int e = e0 + u * 1024 + tid;
        if (e < NE) atomicAdd(&hist[dst[e] >> 8], 1);
    }
    __syncthreads();
    if (tid < NBK) bhist[blk * NBK + tid] = hist[tid];
}

__global__ __launch_bounds__(256) void k_bscan(int* __restrict__ bhist,
                                               int* __restrict__ bbeg,
                                               int* __restrict__ row_ptr) {
    __shared__ int wsum[4];
    const int tid = threadIdx.x;
    int tot = 0;
    if (tid < NBK) {
        for (int c = 0; c < NCH; ++c) {           // coalesced across tid
            int t = bhist[c * NBK + tid];
            bhist[c * NBK + tid] = tot;           // per-bucket chunk prefix
            tot += t;
        }
    }
    const int lane = tid & 63, wid = tid >> 6;
    int x = tot;
    #pragma unroll
    for (int o = 1; o < 64; o <<= 1) {
        int t = __shfl_up(x, o);
        if (lane >= o) x += t;
    }
    if (lane == 63) wsum[wid] = x;
    __syncthreads();
    int wo = 0;
    for (int k = 0; k < wid; ++k) wo += wsum[k];
    const int excl = x - tot + wo;                // bucket start offset
    if (tid < NBK) bbeg[tid] = excl;
    if (tid == 0) { bbeg[NBK] = NE; row_ptr[NN] = NE; }
    __syncthreads();
    if (tid < NBK)
        for (int c = 0; c < NCH; ++c) bhist[c * NBK + tid] += excl;
}

__global__ __launch_bounds__(1024) void k_binscatter(const int* __restrict__ src,
                                                     const int* __restrict__ dst,
                                                     const float* __restrict__ ew,
                                                     const int* __restrict__ bhist,
                                                     uint2* __restrict__ epk) {
    __shared__ int base[NBK];
    __shared__ int lcur[NBK];
    const int tid = threadIdx.x, blk = blockIdx.x;
    if (tid < NBK) { base[tid] = bhist[blk * NBK + tid]; lcur[tid] = 0; }
    __syncthreads();
    const int e0 = blk * CHUNK;
    #pragma unroll
    for (int u = 0; u < CHUNK / 1024; ++u) {
        int e = e0 + u * 1024 + tid;
        if (e < NE) {
            int d = dst[e];
            int s = src[e];
            float w = ew[e];
            int b = d >> 8;
            int pos = base[b] + atomicAdd(&lcur[b], 1);   // LDS atomic only
            epk[pos] = make_uint2((uint32_t)s | ((uint32_t)(d & 255) << 16),
                                  __float_as_uint(w));
        }
    }
}

__global__ __launch_bounds__(256) void k_build(const uint2* __restrict__ epk,
                                               const int* __restrict__ bbeg,
                                               int* __restrict__ row_ptr,
                                               int* __restrict__ col,
                                               float* __restrict__ wsrt) {
    __shared__ int cnt[256];
    __shared__ int cur[256];
    __shared__ int wsum[4];
    const int tid = threadIdx.x, b = blockIdx.x;
    const int n0 = b << 8;
    const int ebeg = bbeg[b], eend = bbeg[b + 1];
    cnt[tid] = 0;
    __syncthreads();
    for (int e = ebeg + tid; e < eend; e += 256)
        atomicAdd(&cnt[(epk[e].x >> 16) & 255], 1);
    __syncthreads();
    const int v = cnt[tid];
    const int lane = tid & 63, wid = tid >> 6;
    int x = v;
    #pragma unroll
    for (int o = 1; o < 64; o <<= 1) {
        int t = __shfl_up(x, o);
        if (lane >= o) x += t;
    }
    if (lane == 63) wsum[wid] = x;
    __syncthreads();
    int wo = 0;
    for (int k = 0; k < wid; ++k) wo += wsum[k];
    const int excl = ebeg + x - v + wo;           // node segment start
    if (n0 + tid < NN) row_ptr[n0 + tid] = excl;
    cur[tid] = excl;
    __syncthreads();
    for (int e = ebeg + tid; e < eend; e += 256) {
        uint2 p = epk[e];
        int dl = (p.x >> 16) & 255;
        int pos = atomicAdd(&cur[dl], 1);
        col[pos]  = (int)(p.x & 0xFFFFu);
        wsrt[pos] = __uint_as_float(p.y);
    }
}

// -------------------------------------- fused weight transpose + bf16 split
// One launch for all 4 matrices. Wlin [FIN][HD] -> T[HD][FIN] at offset 0;
// Wc[l] [HD][HD] -> T[HD][HD] at offset HD*FIN + l*HD*HD.

__global__ void k_split_all(const float* __restrict__ Wlin,
                            const float* __restrict__ Wc,
                            ushort* __restrict__ Th, ushort* __restrict__ Tl) {
    int idx = blockIdx.x * blockDim.x + threadIdx.x;
    const int NLIN = HD * FIN;
    float f;
    if (idx < NLIN) {
        int n = idx / FIN, k = idx - n * FIN;
        f = Wlin[(size_t)k * HD + n];
    } else if (idx < NLIN + 3 * HD * HD) {
        int r = idx - NLIN;
        int l = r / (HD * HD);
        int rr = r - l * (HD * HD);
        int n = rr / HD, k = rr - n * HD;
        f = Wc[(size_t)l * HD * HD + (size_t)k * HD + n];
    } else return;
    ushort hi = f2bf(f);
    Th[idx] = hi;
    Tl[idx] = f2bf(f - bf2f(hi));
}

// ----------------------------------------------------- MFMA split-bf16 GEMM
// C[M][128] = A[M][K] @ B[K][128] (+bias), 16x16x32 bf16 MFMA,
// D = Ahi*Bhi + Ahi*Blo + Alo*Bhi  (~fp32 accuracy).
// Round-8 config (best measured): B^T hi/lo for a whole BK=128 K-tile staged
// ONCE into 64 KB LDS (XOR-swizzled 16B chunks), barrier-free main loop,
// 4 waves x 32 rows, grid 391.

template <int K, bool ATT>
__global__ __launch_bounds__(256) void k_gemm_mfma(
    const float*  __restrict__ A,
    const ushort* __restrict__ Bh,     // [HD][K]
    const ushort* __restrict__ Bl,     // [HD][K]
    const float*  __restrict__ bias,   // null if none
    float*        __restrict__ Cf,     // fp32 out (null if unused)
    ushort*       __restrict__ Cb,     // bf16 out (null if unused)
    const float*  __restrict__ att_s, const float* __restrict__ att_d,
    float* __restrict__ as_, float* __restrict__ ad_,
    int M)
{
    constexpr int BK = 128;                       // K-elems per LDS tile
    constexpr int NT = K / BK;                    // 1 or 2 tiles
    __shared__ ushort Bs[32768];                  // 64 KB: hi [0..16383], lo +16384

    const int tid  = threadIdx.x;
    const int lane = tid & 63;
    const int wid  = tid >> 6;
    const int fl   = lane & 15;                   // A row / B col within frag
    const int fg   = lane >> 4;                   // k-group (8 elems)
    const int rowBase = blockIdx.x * 128 + wid * 32;

    f32x4 acc[2][8] = {};

    for (int t = 0; t < NT; ++t) {
        if (t) __syncthreads();                   // all waves done with tile t-1
        #pragma unroll
        for (int u = 0; u < 8; ++u) {
            const int id  = u * 256 + tid;
            const int bcol = id >> 4, c = id & 15;
            const size_t g = (size_t)bcol * K + t * BK + c * 8;
            const int lidx = bcol * 128 + ((c ^ (bcol & 15)) << 3);
            *reinterpret_cast<uint4*>(&Bs[lidx]) =
                *reinterpret_cast<const uint4*>(Bh + g);
            *reinterpret_cast<uint4*>(&Bs[16384 + lidx]) =
                *reinterpret_cast<const uint4*>(Bl + g);
        }
        __syncthreads();

        #pragma unroll
        for (int kt = 0; kt < BK / 32; ++kt) {
            s16x8 a_h[2], a_l[2];
            #pragma unroll
            for (int rt = 0; rt < 2; ++rt) {
                int r = rowBase + rt * 16 + fl;
                if (r >= M) r = M - 1;            // harmless clamp (stores guarded)
                const float* ap = A + (size_t)r * K + t * BK + kt * 32 + fg * 8;
                float4 t0 = *reinterpret_cast<const float4*>(ap);
                float4 t1 = *reinterpret_cast<const float4*>(ap + 4);
                float v[8] = {t0.x, t0.y, t0.z, t0.w, t1.x, t1.y, t1.z, t1.w};
                #pragma unroll
                for (int u = 0; u < 8; ++u) {
                    ushort h0 = f2bf(v[u]);
                    a_h[rt][u] = (short)h0;
                    a_l[rt][u] = (short)f2bf(v[u] - bf2f(h0));
                }
            }
            #pragma unroll
            for (int ct = 0; ct < 8; ++ct) {
                const int lidx = (ct * 16 + fl) * 128 + (((kt * 4 + fg) ^ fl) << 3);
                s16x8 b_h = *reinterpret_cast<const s16x8*>(&Bs[lidx]);
                s16x8 b_l = *reinterpret_cast<const s16x8*>(&Bs[16384 + lidx]);
                #pragma unroll
                for (int rt = 0; rt < 2; ++rt) {
                    acc[rt][ct] = __builtin_amdgcn_mfma_f32_16x16x32_bf16(a_h[rt], b_h, acc[rt][ct], 0, 0, 0);
                    acc[rt][ct] = __builtin_amdgcn_mfma_f32_16x16x32_bf16(a_h[rt], b_l, acc[rt][ct], 0, 0, 0);
                    acc[rt][ct] = __builtin_amdgcn_mfma_f32_16x16x32_bf16(a_l[rt], b_h, acc[rt][ct], 0, 0, 0);
                }
            }
        }
    }

    // ---- epilogue: C/D layout col = ct*16 + fl, row = base + fg*4 + reg ----
    float bval[8];
    #pragma unroll
    for (int ct = 0; ct < 8; ++ct) bval[ct] = bias ? bias[ct * 16 + fl] : 0.f;
    float asv[8], adv[8];
    if (ATT) {
        #pragma unroll
        for (int ct = 0; ct < 8; ++ct) {
            asv[ct] = att_s[ct * 16 + fl];
            adv[ct] = att_d[ct * 16 + fl];
        }
    }

    #pragma unroll
    for (int rt = 0; rt < 2; ++rt) {
        const int rbase = rowBase + rt * 16 + fg * 4;
        #pragma unroll
        for (int r = 0; r < 4; ++r) {
            const int row = rbase + r;
            const bool ok = row < M;
            float sv = 0.f, dv = 0.f;
            #pragma unroll
            for (int ct = 0; ct < 8; ++ct) {
                float val = acc[rt][ct][r] + bval[ct];
                if (ATT) { sv = fmaf(val, asv[ct], sv); dv = fmaf(val, adv[ct], dv); }
                if (ok) {
                    if (Cf) Cf[(size_t)row * HD + ct * 16 + fl] = val;
                    if (Cb) Cb[(size_t)row * HD + ct * 16 + fl] = f2bf(val);
                }
            }
            if (ATT) {
                #pragma unroll
                for (int o = 1; o < 16; o <<= 1) {    // reduce within 16-lane group
                    sv += __shfl_xor(sv, o);
                    dv += __shfl_xor(dv, o);
                }
                if (fl == 0 && ok) { as_[row] = sv; ad_[row] = dv; }
            }
        }
    }
}

// ---------------------------------------------- fused softmax-aggregation
// One wave per destination node (round-8 structure, uint4 variant):
// lane owns 8 features (uint4 = 16 B), 16 lanes cover a row, the 4 wave
// quarters process 4 edges per load instruction. 4 loads = 16 edges in
// flight. No segment-max pass (softmax shift-invariant; l clamped 80).
// Final __shfl_xor(32),(16) folds quarters; lanes 0-15 store 2x float4.
// mode: 0 = h += agg (no out); 1 = out = max(h_old, h_old+agg), h += agg;
// 2 = out = max(out, agg + b).

__global__ __launch_bounds__(256) void k_agg(const ushort* __restrict__ hpb,
                                             float* __restrict__ h,
                                             const float* __restrict__ as_,
                                             const float* __restrict__ ad_,
                                             const int* __restrict__ row_ptr,
                                             const int* __restrict__ col,
                                             const float* __restrict__ wsrt,
                                             const float* __restrict__ bias,
                                             float* __restrict__ out, int mode) {
    int wave = (blockIdx.x * blockDim.x + threadIdx.x) >> 6;
    int lane = threadIdx.x & 63;
    if (wave >= NN) return;
    const int d = wave;
    const int beg = row_ptr[d], end = row_ptr[d + 1];
    const float adv = ad_[d];
    const int q  = lane >> 4;          // which of 4 concurrent edges
    const int hl = lane & 15;          // feature octet: owns [hl*8, hl*8+8)

    float a0 = 0.f, a1 = 0.f, a2 = 0.f, a3 = 0.f;
    float a4 = 0.f, a5 = 0.f, a6 = 0.f, a7 = 0.f, dloc = 0.f;

    for (int base = beg; base < end; base += 64) {
        const int n = min(64, end - base);
        int s = 0; float w = 0.f;
        if (lane < n) {
            s = col[base + lane];
            float l = as_[s] + adv;
            l = (l >= 0.f) ? l : NEG_SLOPE * l;
            l = fminf(l, 80.f);                    // overflow guard (no max pass)
            w = __expf(l) * wsrt[base + lane];
        }
        dloc += w;

        int i = 0;
        for (; i + 15 < n; i += 16) {          // 16 edges = 4 quad loads in flight
            float wv[4]; int sv[4]; uint4 pv[4];
            #pragma unroll
            for (int j = 0; j < 4; ++j) {
                const int idx = i + 4 * j + q;
                wv[j] = __shfl(w, idx);
                sv[j] = __shfl(s, idx);
            }
            #pragma unroll
            for (int j = 0; j < 4; ++j)
                pv[j] = *reinterpret_cast<const uint4*>(hpb + (size_t)sv[j] * HD + hl * 8);
            #pragma unroll
            for (int j = 0; j < 4; ++j) {
                a0 = fmaf(wv[j], bf2f((ushort)pv[j].x),         a0);
                a1 = fmaf(wv[j], bf2f((ushort)(pv[j].x >> 16)), a1);
                a2 = fmaf(wv[j], bf2f((ushort)pv[j].y),         a2);
                a3 = fmaf(wv[j], bf2f((ushort)(pv[j].y >> 16)), a3);
                a4 = fmaf(wv[j], bf2f((ushort)pv[j].z),         a4);
                a5 = fmaf(wv[j], bf2f((ushort)(pv[j].z >> 16)), a5);
                a6 = fmaf(wv[j], bf2f((ushort)pv[j].w),         a6);
                a7 = fmaf(wv[j], bf2f((ushort)(pv[j].w >> 16)), a7);
            }
        }
        for (; i + 3 < n; i += 4) {            // 4-edge steps
            const int idx = i + q;
            float wj = __shfl(w, idx);
            int   sj = __shfl(s, idx);
            uint4 pv = *reinterpret_cast<const uint4*>(hpb + (size_t)sj * HD + hl * 8);
            a0 = fmaf(wj, bf2f((ushort)pv.x),         a0);
            a1 = fmaf(wj, bf2f((ushort)(pv.x >> 16)), a1);
            a2 = fmaf(wj, bf2f((ushort)pv.y),         a2);
            a3 = fmaf(wj, bf2f((ushort)(pv.y >> 16)), a3);
            a4 = fmaf(wj, bf2f((ushort)pv.z),         a4);
            a5 = fmaf(wj, bf2f((ushort)(pv.z >> 16)), a5);
            a6 = fmaf(wj, bf2f((ushort)pv.w),         a6);
            a7 = fmaf(wj, bf2f((ushort)(pv.w >> 16)), a7);
        }
        if (i < n) {                           // tail < 4 edges (masked)
            const int e = i + q;
            const bool ok = e < n;
            const int idx = ok ? e : i;
            float wj = __shfl(w, idx);
            int   sj = __shfl(s, idx);
            if (!ok) wj = 0.f;
            uint4 pv = *reinterpret_cast<const uint4*>(hpb + (size_t)sj * HD + hl * 8);
            a0 = fmaf(wj, bf2f((ushort)pv.x),         a0);
            a1 = fmaf(wj, bf2f((ushort)(pv.x >> 16)), a1);
            a2 = fmaf(wj, bf2f((ushort)pv.y),         a2);
            a3 = fmaf(wj, bf2f((ushort)(pv.y >> 16)), a3);
            a4 = fmaf(wj, bf2f((ushort)pv.z),         a4);
            a5 = fmaf(wj, bf2f((ushort)(pv.z >> 16)), a5);
            a6 = fmaf(wj, bf2f((ushort)pv.w),         a6);
            a7 = fmaf(wj, bf2f((ushort)(pv.w >> 16)), a7);
        }
    }
    #pragma unroll
    for (int o = 32; o > 0; o >>= 1) dloc += __shfl_xor(dloc, o);
    #pragma unroll
    for (int o = 32; o >= 16; o >>= 1) {
        a0 += __shfl_xor(a0, o); a1 += __shfl_xor(a1, o);
        a2 += __shfl_xor(a2, o); a3 += __shfl_xor(a3, o);
        a4 += __shfl_xor(a4, o); a5 += __shfl_xor(a5, o);
        a6 += __shfl_xor(a6, o); a7 += __shfl_xor(a7, o);
    }

    if (q != 0) return;                        // lanes 0-15 do the stores
    const float inv = 1.f / (dloc + 1e-16f);
    const int f0 = hl * 8;
    float4 r0, r1;
    r0.x = a0 * inv + bias[f0 + 0]; r0.y = a1 * inv + bias[f0 + 1];
    r0.z = a2 * inv + bias[f0 + 2]; r0.w = a3 * inv + bias[f0 + 3];
    r1.x = a4 * inv + bias[f0 + 4]; r1.y = a5 * inv + bias[f0 + 5];
    r1.z = a6 * inv + bias[f0 + 6]; r1.w = a7 * inv + bias[f0 + 7];

    float4* outp = reinterpret_cast<float4*>(out + (size_t)d * HD + f0);
    float4* hp4  = reinterpret_cast<float4*>(h   + (size_t)d * HD + f0);
    if (mode == 2) {
        float4 o0 = outp[0], o1 = outp[1];
        o0.x = fmaxf(o0.x, r0.x); o0.y = fmaxf(o0.y, r0.y);
        o0.z = fmaxf(o0.z, r0.z); o0.w = fmaxf(o0.w, r0.w);
        o1.x = fmaxf(o1.x, r1.x); o1.y = fmaxf(o1.y, r1.y);
        o1.z = fmaxf(o1.z, r1.z); o1.w = fmaxf(o1.w, r1.w);
        outp[0] = o0; outp[1] = o1;
    } else {
        float4 hv0 = hp4[0], hv1 = hp4[1];
        float4 hn0, hn1;
        hn0.x = hv0.x + r0.x; hn0.y = hv0.y + r0.y;
        hn0.z = hv0.z + r0.z; hn0.w = hv0.w + r0.w;
        hn1.x = hv1.x + r1.x; hn1.y = hv1.y + r1.y;
        hn1.z = hv1.z + r1.z; hn1.w = hv1.w + r1.w;
        hp4[0] = hn0; hp4[1] = hn1;
        if (mode == 1) {                        // out = max(h1, h2), no out read
            float4 m0, m1;
            m0.x = fmaxf(hv0.x, hn0.x); m0.y = fmaxf(hv0.y, hn0.y);
            m0.z = fmaxf(hv0.z, hn0.z); m0.w = fmaxf(hv0.w, hn0.w);
            m1.x = fmaxf(hv1.x, hn1.x); m1.y = fmaxf(hv1.y, hn1.y);
            m1.z = fmaxf(hv1.z, hn1.z); m1.w = fmaxf(hv1.w, hn1.w);
            outp[0] = m0; outp[1] = m1;
        }
    }
}

// ---------------------------------------------------------------- launch

extern "C" void kernel_launch(void* const* d_in, const int* in_sizes, int n_in,
                              void* d_out, int out_size, void* d_ws, size_t ws_size,
                              hipStream_t stream) {
    const float* x        = (const float*)d_in[0];          // [NN][FIN]
    const int*   ei       = (const int*)d_in[1];            // [2][NE]
    const float* ew       = (const float*)d_in[2];          // [NE]
    /* d_in[3] = numNode scalar = NN */
    const float* Wlin     = (const float*)d_in[4];          // [FIN][HD]
    const float* blin     = (const float*)d_in[5];          // [HD]
    const float* Wc       = (const float*)d_in[6];          // [3][HD][HD]
    const float* att_src  = (const float*)d_in[7];          // [3][HD]
    const float* att_dst  = (const float*)d_in[8];          // [3][HD]
    const float* bias_c   = (const float*)d_in[9];          // [3][HD]
    float* out = (float*)d_out;                              // [NN][HD]

    const int* src = ei;
    const int* dst = ei + NE;

    // workspace layout (16B-aligned blocks, ~52 MB)
    char* w = (char*)d_ws;
    float*  h       = (float*)w;   w += (size_t)NN * HD * 4;
    ushort* hpb     = (ushort*)w;  w += (size_t)NN * HD * 2;
    float*  as_     = (float*)w;   w += (size_t)NN * 4;
    float*  ad_     = (float*)w;   w += (size_t)NN * 4;
    int*    row_ptr = (int*)w;     w += (size_t)(NN + 4) * 4;
    int*    col     = (int*)w;     w += (size_t)NE * 4;
    float*  wsrt    = (float*)w;   w += (size_t)NE * 4;
    uint2*  epk     = (uint2*)w;   w += (size_t)NE * 8;
    int*    bhist   = (int*)w;     w += (size_t)NCH * NBK * 4;
    int*    bbeg    = (int*)w;     w += (size_t)(NBK + 4) * 4;
    ushort* WTh     = (ushort*)w;  w += (size_t)(HD * FIN + 3 * HD * HD) * 2;
    ushort* WTl     = (ushort*)w;  w += (size_t)(HD * FIN + 3 * HD * HD) * 2;
    ushort* WlinTh = WTh,            *WlinTl = WTl;
    ushort* WcTh   = WTh + HD * FIN, *WcTl   = WTl + HD * FIN;

    const int TB = 256;
    const int nblk_w = (NN * 64 + TB - 1) / TB;      // one wave per node
    const int nblk_g = (NN + 127) / 128;             // 391 (128 rows per block)
    const int nsplit = HD * FIN + 3 * HD * HD;       // all weight elements

    // ---- fused weight transpose + split (1 launch) ----
    k_split_all<<<(nsplit + TB - 1) / TB, TB, 0, stream>>>(Wlin, Wc, WTh, WTl);

    // ---- CSR build (atomic-reservation-free binning) ----
    k_bhist<<<NCH, 1024, 0, stream>>>(dst, bhist);
    k_bscan<<<1, 256, 0, stream>>>(bhist, bbeg, row_ptr);
    k_binscatter<<<NCH, 1024, 0, stream>>>(src, dst, ew, bhist, epk);
    k_build<<<NBK, 256, 0, stream>>>(epk, bbeg, row_ptr, col, wsrt);

    // ---- input projection: h = x @ Wlin + blin (fp32 out) ----
    k_gemm_mfma<FIN, false><<<nblk_g, TB, 0, stream>>>(
        x, WlinTh, WlinTl, blin, h, nullptr, nullptr, nullptr, nullptr, nullptr, NN);

    // ---- 3 GAT layers ----
    for (int layer = 0; layer < 3; ++layer) {
        k_gemm_mfma<HD, true><<<nblk_g, TB, 0, stream>>>(
            h, WcTh + (size_t)layer * HD * HD, WcTl + (size_t)layer * HD * HD,
            nullptr, nullptr, hpb,
            att_src + layer * HD, att_dst + layer * HD, as_, ad_, NN);
        int mode = (layer == 0) ? 0 : (layer == 2 ? 2 : 1);
        k_agg<<<nblk_w, TB, 0, stream>>>(hpb, h, as_, ad_, row_ptr, col, wsrt,
                                         bias_c + layer * HD, out, mode);
    }
}

// Round 13
// 219.932 us; speedup vs baseline: 1.7939x; 1.0763x over previous
//
#include <hip/hip_runtime.h>
#include <cstdint>
#include <cstddef>

// Problem constants (from reference)
#define NN 50000
#define NE 800000
#define FIN 256
#define HD 128
#define NEG_SLOPE 0.2f

// CSR-build binning parameters
#define NBK 196          // buckets of 256 nodes: ceil(50000/256)
#define NCH 98           // edge chunks
#define NCHP 104         // padded chunk count (mult of 4 for int4 scan)
#define CHUNK 8192       // edges per chunk (98*8192 >= 800000)

typedef short s16x8 __attribute__((ext_vector_type(8)));   // 8 bf16 (4 VGPRs)
typedef float f32x4 __attribute__((ext_vector_type(4)));   // MFMA accumulator

__device__ inline ushort f2bf(float f) {                   // fp32 -> bf16 RTN-even
    uint32_t u = __float_as_uint(f);
    u += 0x7FFFu + ((u >> 16) & 1u);
    return (ushort)(u >> 16);
}
__device__ inline float bf2f(ushort h) {
    return __uint_as_float(((uint32_t)h) << 16);
}

// ------------------------------------------------------------- CSR build
// bucket = dst >> 8. No global atomics anywhere.
// bhist layout: [bucket][NCHP] (transposed) so the scan kernel loads each
// bucket's row as 26 independent int4s (pipelined) instead of 98 serial
// load/store alternations.

__global__ __launch_bounds__(1024) void k_bhist(const int* __restrict__ dst,
                                                int* __restrict__ bhist) {
    __shared__ int hist[NBK];
    const int tid = threadIdx.x, blk = blockIdx.x;
    if (tid < NBK) hist[tid] = 0;
    __syncthreads();
    const int e0 = blk * CHUNK;
    #pragma unroll
    for (int u = 0; u < CHUNK / 1024; ++u) {
        int e = e0 + u * 1024 + tid;
        if (e < NE) atomicAdd(&hist[dst[e] >> 8], 1);
    }
    __syncthreads();
    if (tid < NBK) {
        bhist[tid * NCHP + blk] = hist[tid];
        if (blk == 0)                          // zero the scan padding once
            for (int c = NCH; c < NCHP; ++c) bhist[tid * NCHP + c] = 0;
    }
}

__global__ __launch_bounds__(256) void k_bscan(int* __restrict__ bhist,
                                               int* __restrict__ bbeg,
                                               int* __restrict__ row_ptr) {
    __shared__ int wsum[4];
    const int tid = threadIdx.x;
    int4 buf[NCHP / 4];
    int tot = 0;
    if (tid < NBK) {
        const int4* rp = reinterpret_cast<const int4*>(bhist + tid * NCHP);
        #pragma unroll
        for (int u = 0; u < NCHP / 4; ++u) buf[u] = rp[u];     // independent loads
        #pragma unroll
        for (int u = 0; u < NCHP / 4; ++u) {                   // exclusive scan in regs
            int4 v = buf[u], o;
            o.x = tot; tot += v.x;
            o.y = tot; tot += v.y;
            o.z = tot; tot += v.z;
            o.w = tot; tot += v.w;
            buf[u] = o;
        }
    }
    const int lane = tid & 63, wid = tid >> 6;
    int x = tot;
    #pragma unroll
    for (int o = 1; o < 64; o <<= 1) {
        int t = __shfl_up(x, o);
        if (lane >= o) x += t;
    }
    if (lane == 63) wsum[wid] = x;
    __syncthreads();
    int wo = 0;
    for (int k = 0; k < wid; ++k) wo += wsum[k];
    const int excl = x - tot + wo;                // bucket start offset
    if (tid < NBK) {
        bbeg[tid] = excl;
        int4* rp = reinterpret_cast<int4*>(bhist + tid * NCHP);
        #pragma unroll
        for (int u = 0; u < NCHP / 4; ++u) {
            int4 v = buf[u];
            v.x += excl; v.y += excl; v.z += excl; v.w += excl;
            rp[u] = v;
        }
    }
    if (tid == 0) { bbeg[NBK] = NE; row_ptr[NN] = NE; }
}

__global__ __launch_bounds__(1024) void k_binscatter(const int* __restrict__ src,
                                                     const int* __restrict__ dst,
                                                     const float* __restrict__ ew,
                                                     const int* __restrict__ bhist,
                                                     uint2* __restrict__ epk) {
    __shared__ int base[NBK];
    __shared__ int lcur[NBK];
    const int tid = threadIdx.x, blk = blockIdx.x;
    if (tid < NBK) { base[tid] = bhist[tid * NCHP + blk]; lcur[tid] = 0; }
    __syncthreads();
    const int e0 = blk * CHUNK;
    #pragma unroll
    for (int u = 0; u < CHUNK / 1024; ++u) {
        int e = e0 + u * 1024 + tid;
        if (e < NE) {
            int d = dst[e];
            int s = src[e];
            float w = ew[e];
            int b = d >> 8;
            int pos = base[b] + atomicAdd(&lcur[b], 1);   // LDS atomic only
            epk[pos] = make_uint2((uint32_t)s | ((uint32_t)(d & 255) << 16),
                                  __float_as_uint(w));
        }
    }
}

__global__ __launch_bounds__(256) void k_build(const uint2* __restrict__ epk,
                                               const int* __restrict__ bbeg,
                                               int* __restrict__ row_ptr,
                                               unsigned int* __restrict__ cw) {
    __shared__ int cnt[256];
    __shared__ int cur[256];
    __shared__ int wsum[4];
    const int tid = threadIdx.x, b = blockIdx.x;
    const int n0 = b << 8;
    const int ebeg = bbeg[b], eend = bbeg[b + 1];
    cnt[tid] = 0;
    __syncthreads();
    for (int e = ebeg + tid; e < eend; e += 256)
        atomicAdd(&cnt[(epk[e].x >> 16) & 255], 1);
    __syncthreads();
    const int v = cnt[tid];
    const int lane = tid & 63, wid = tid >> 6;
    int x = v;
    #pragma unroll
    for (int o = 1; o < 64; o <<= 1) {
        int t = __shfl_up(x, o);
        if (lane >= o) x += t;
    }
    if (lane == 63) wsum[wid] = x;
    __syncthreads();
    int wo = 0;
    for (int k = 0; k < wid; ++k) wo += wsum[k];
    const int excl = ebeg + x - v + wo;           // node segment start
    if (n0 + tid < NN) row_ptr[n0 + tid] = excl;
    cur[tid] = excl;
    __syncthreads();
    for (int e = ebeg + tid; e < eend; e += 256) {
        uint2 p = epk[e];
        int dl = (p.x >> 16) & 255;
        int pos = atomicAdd(&cur[dl], 1);
        // packed edge: low16 = src, high16 = bf16(edge_weight)
        cw[pos] = (p.x & 0xFFFFu) |
                  ((unsigned int)f2bf(__uint_as_float(p.y)) << 16);
    }
}

// -------------------------------------- fused weight transpose + bf16 split
// One launch for all 4 matrices. Wlin [FIN][HD] -> T[HD][FIN] at offset 0;
// Wc[l] [HD][HD] -> T[HD][HD] at offset HD*FIN + l*HD*HD.

__global__ void k_split_all(const float* __restrict__ Wlin,
                            const float* __restrict__ Wc,
                            ushort* __restrict__ Th, ushort* __restrict__ Tl) {
    int idx = blockIdx.x * blockDim.x + threadIdx.x;
    const int NLIN = HD * FIN;
    float f;
    if (idx < NLIN) {
        int n = idx / FIN, k = idx - n * FIN;
        f = Wlin[(size_t)k * HD + n];
    } else if (idx < NLIN + 3 * HD * HD) {
        int r = idx - NLIN;
        int l = r / (HD * HD);
        int rr = r - l * (HD * HD);
        int n = rr / HD, k = rr - n * HD;
        f = Wc[(size_t)l * HD * HD + (size_t)k * HD + n];
    } else return;
    ushort hi = f2bf(f);
    Th[idx] = hi;
    Tl[idx] = f2bf(f - bf2f(hi));
}

// ----------------------------------------------------- MFMA split-bf16 GEMM
// C[M][128] = A[M][K] @ B[K][128] (+bias), 16x16x32 bf16 MFMA, bf16 out.
// ABF16=false: A fp32, split hi/lo in-flight, D = Ah*Bh + Ah*Bl + Al*Bh.
// ABF16=true:  A already bf16 (exact) -> a_l == 0: one 16B A-load and only
//              2 MFMA per col-tile (D = A*Bh + A*Bl).
// B^T hi/lo for a whole BK=128 K-tile staged ONCE into 64 KB LDS
// (XOR-swizzled 16B chunks), barrier-free main loop, 4 waves x 32 rows.

template <int K, bool ATT, bool ABF16>
__global__ __launch_bounds__(256) void k_gemm_mfma(
    const float*  __restrict__ Af,     // fp32 A (ABF16=false)
    const ushort* __restrict__ Ab,     // bf16 A (ABF16=true)
    const ushort* __restrict__ Bh,     // [HD][K]
    const ushort* __restrict__ Bl,     // [HD][K]
    const float*  __restrict__ bias,   // null if none
    ushort*       __restrict__ Cb,     // bf16 out
    const float*  __restrict__ att_s, const float* __restrict__ att_d,
    float* __restrict__ as_, float* __restrict__ ad_,
    int M)
{
    constexpr int BK = 128;                       // K-elems per LDS tile
    constexpr int NT = K / BK;                    // 1 or 2 tiles
    __shared__ ushort Bs[32768];                  // 64 KB: hi [0..16383], lo +16384

    const int tid  = threadIdx.x;
    const int lane = tid & 63;
    const int wid  = tid >> 6;
    const int fl   = lane & 15;                   // A row / B col within frag
    const int fg   = lane >> 4;                   // k-group (8 elems)
    const int rowBase = blockIdx.x * 128 + wid * 32;

    f32x4 acc[2][8] = {};

    for (int t = 0; t < NT; ++t) {
        if (t) __syncthreads();                   // all waves done with tile t-1
        #pragma unroll
        for (int u = 0; u < 8; ++u) {
            const int id  = u * 256 + tid;
            const int bcol = id >> 4, c = id & 15;
            const size_t g = (size_t)bcol * K + t * BK + c * 8;
            const int lidx = bcol * 128 + ((c ^ (bcol & 15)) << 3);
            *reinterpret_cast<uint4*>(&Bs[lidx]) =
                *reinterpret_cast<const uint4*>(Bh + g);
            *reinterpret_cast<uint4*>(&Bs[16384 + lidx]) =
                *reinterpret_cast<const uint4*>(Bl + g);
        }
        __syncthreads();

        #pragma unroll
        for (int kt = 0; kt < BK / 32; ++kt) {
            s16x8 a_h[2], a_l[2];
            #pragma unroll
            for (int rt = 0; rt < 2; ++rt) {
                int r = rowBase + rt * 16 + fl;
                if (r >= M) r = M - 1;            // harmless clamp (stores guarded)
                if (ABF16) {
                    a_h[rt] = *reinterpret_cast<const s16x8*>(
                        Ab + (size_t)r * K + t * BK + kt * 32 + fg * 8);
                } else {
                    const float* ap = Af + (size_t)r * K + t * BK + kt * 32 + fg * 8;
                    float4 t0 = *reinterpret_cast<const float4*>(ap);
                    float4 t1 = *reinterpret_cast<const float4*>(ap + 4);
                    float v[8] = {t0.x, t0.y, t0.z, t0.w, t1.x, t1.y, t1.z, t1.w};
                    #pragma unroll
                    for (int u = 0; u < 8; ++u) {
                        ushort h0 = f2bf(v[u]);
                        a_h[rt][u] = (short)h0;
                        a_l[rt][u] = (short)f2bf(v[u] - bf2f(h0));
                    }
                }
            }
            #pragma unroll
            for (int ct = 0; ct < 8; ++ct) {
                const int lidx = (ct * 16 + fl) * 128 + (((kt * 4 + fg) ^ fl) << 3);
                s16x8 b_h = *reinterpret_cast<const s16x8*>(&Bs[lidx]);
                s16x8 b_l = *reinterpret_cast<const s16x8*>(&Bs[16384 + lidx]);
                #pragma unroll
                for (int rt = 0; rt < 2; ++rt) {
                    acc[rt][ct] = __builtin_amdgcn_mfma_f32_16x16x32_bf16(a_h[rt], b_h, acc[rt][ct], 0, 0, 0);
                    acc[rt][ct] = __builtin_amdgcn_mfma_f32_16x16x32_bf16(a_h[rt], b_l, acc[rt][ct], 0, 0, 0);
                    if (!ABF16)
                        acc[rt][ct] = __builtin_amdgcn_mfma_f32_16x16x32_bf16(a_l[rt], b_h, acc[rt][ct], 0, 0, 0);
                }
            }
        }
    }

    // ---- epilogue: C/D layout col = ct*16 + fl, row = base + fg*4 + reg ----
    float bval[8];
    #pragma unroll
    for (int ct = 0; ct < 8; ++ct) bval[ct] = bias ? bias[ct * 16 + fl] : 0.f;
    float asv[8], adv[8];
    if (ATT) {
        #pragma unroll
        for (int ct = 0; ct < 8; ++ct) {
            asv[ct] = att_s[ct * 16 + fl];
            adv[ct] = att_d[ct * 16 + fl];
        }
    }

    #pragma unroll
    for (int rt = 0; rt < 2; ++rt) {
        const int rbase = rowBase + rt * 16 + fg * 4;
        #pragma unroll
        for (int r = 0; r < 4; ++r) {
            const int row = rbase + r;
            const bool ok = row < M;
            float sv = 0.f, dv = 0.f;
            #pragma unroll
            for (int ct = 0; ct < 8; ++ct) {
                float val = acc[rt][ct][r] + bval[ct];
                if (ATT) { sv = fmaf(val, asv[ct], sv); dv = fmaf(val, adv[ct], dv); }
                if (ok) Cb[(size_t)row * HD + ct * 16 + fl] = f2bf(val);
            }
            if (ATT) {
                #pragma unroll
                for (int o = 1; o < 16; o <<= 1) {    // reduce within 16-lane group
                    sv += __shfl_xor(sv, o);
                    dv += __shfl_xor(dv, o);
                }
                if (fl == 0 && ok) { as_[row] = sv; ad_[row] = dv; }
            }
        }
    }
}

// ---------------------------------------------- fused softmax-aggregation
// One wave per destination node (round-12 structure): lane owns 8 features
// (uint4 = 16 B), 16 lanes cover a row, the 4 wave quarters process 4 edges
// per load instruction (16 edges in flight). Edge metadata is one packed
// uint (col | bf16(ew)<<16). h is stored bf16. No segment-max pass
// (softmax shift-invariant; l clamped 80).
// mode: 0 = h += agg (no out); 1 = out = max(h_old, h_old+agg), h += agg;
// 2 = out = max(out, agg + b).

__global__ __launch_bounds__(256) void k_agg(const ushort* __restrict__ hpb,
                                             ushort* __restrict__ hb,
                                             const float* __restrict__ as_,
                                             const float* __restrict__ ad_,
                                             const int* __restrict__ row_ptr,
                                             const unsigned int* __restrict__ cw,
                                             const float* __restrict__ bias,
                                             float* __restrict__ out, int mode) {
    int wave = (blockIdx.x * blockDim.x + threadIdx.x) >> 6;
    int lane = threadIdx.x & 63;
    if (wave >= NN) return;
    const int d = wave;
    const int beg = row_ptr[d], end = row_ptr[d + 1];
    const float adv = ad_[d];
    const int q  = lane >> 4;          // which of 4 concurrent edges
    const int hl = lane & 15;          // feature octet: owns [hl*8, hl*8+8)

    float a0 = 0.f, a1 = 0.f, a2 = 0.f, a3 = 0.f;
    float a4 = 0.f, a5 = 0.f, a6 = 0.f, a7 = 0.f, dloc = 0.f;

    for (int base = beg; base < end; base += 64) {
        const int n = min(64, end - base);
        int s = 0; float w = 0.f;
        if (lane < n) {
            unsigned int v = cw[base + lane];
            s = (int)(v & 0xFFFFu);
            float l = as_[s] + adv;
            l = (l >= 0.f) ? l : NEG_SLOPE * l;
            l = fminf(l, 80.f);                    // overflow guard (no max pass)
            w = __expf(l) * bf2f((ushort)(v >> 16));
        }
        dloc += w;

        int i = 0;
        for (; i + 15 < n; i += 16) {          // 16 edges = 4 quad loads in flight
            float wv[4]; int sv[4]; uint4 pv[4];
            #pragma unroll
            for (int j = 0; j < 4; ++j) {
                const int idx = i + 4 * j + q;
                wv[j] = __shfl(w, idx);
                sv[j] = __shfl(s, idx);
            }
            #pragma unroll
            for (int j = 0; j < 4; ++j)
                pv[j] = *reinterpret_cast<const uint4*>(hpb + (size_t)sv[j] * HD + hl * 8);
            #pragma unroll
            for (int j = 0; j < 4; ++j) {
                a0 = fmaf(wv[j], bf2f((ushort)pv[j].x),         a0);
                a1 = fmaf(wv[j], bf2f((ushort)(pv[j].x >> 16)), a1);
                a2 = fmaf(wv[j], bf2f((ushort)pv[j].y),         a2);
                a3 = fmaf(wv[j], bf2f((ushort)(pv[j].y >> 16)), a3);
                a4 = fmaf(wv[j], bf2f((ushort)pv[j].z),         a4);
                a5 = fmaf(wv[j], bf2f((ushort)(pv[j].z >> 16)), a5);
                a6 = fmaf(wv[j], bf2f((ushort)pv[j].w),         a6);
                a7 = fmaf(wv[j], bf2f((ushort)(pv[j].w >> 16)), a7);
            }
        }
        for (; i + 3 < n; i += 4) {            // 4-edge steps
            const int idx = i + q;
            float wj = __shfl(w, idx);
            int   sj = __shfl(s, idx);
            uint4 pv = *reinterpret_cast<const uint4*>(hpb + (size_t)sj * HD + hl * 8);
            a0 = fmaf(wj, bf2f((ushort)pv.x),         a0);
            a1 = fmaf(wj, bf2f((ushort)(pv.x >> 16)), a1);
            a2 = fmaf(wj, bf2f((ushort)pv.y),         a2);
            a3 = fmaf(wj, bf2f((ushort)(pv.y >> 16)), a3);
            a4 = fmaf(wj, bf2f((ushort)pv.z),         a4);
            a5 = fmaf(wj, bf2f((ushort)(pv.z >> 16)), a5);
            a6 = fmaf(wj, bf2f((ushort)pv.w),         a6);
            a7 = fmaf(wj, bf2f((ushort)(pv.w >> 16)), a7);
        }
        if (i < n) {                           // tail < 4 edges (masked)
            const int e = i + q;
            const bool ok = e < n;
            const int idx = ok ? e : i;
            float wj = __shfl(w, idx);
            int   sj = __shfl(s, idx);
            if (!ok) wj = 0.f;
            uint4 pv = *reinterpret_cast<const uint4*>(hpb + (size_t)sj * HD + hl * 8);
            a0 = fmaf(wj, bf2f((ushort)pv.x),         a0);
            a1 = fmaf(wj, bf2f((ushort)(pv.x >> 16)), a1);
            a2 = fmaf(wj, bf2f((ushort)pv.y),         a2);
            a3 = fmaf(wj, bf2f((ushort)(pv.y >> 16)), a3);
            a4 = fmaf(wj, bf2f((ushort)pv.z),         a4);
            a5 = fmaf(wj, bf2f((ushort)(pv.z >> 16)), a5);
            a6 = fmaf(wj, bf2f((ushort)pv.w),         a6);
            a7 = fmaf(wj, bf2f((ushort)(pv.w >> 16)), a7);
        }
    }
    #pragma unroll
    for (int o = 32; o > 0; o >>= 1) dloc += __shfl_xor(dloc, o);
    #pragma unroll
    for (int o = 32; o >= 16; o >>= 1) {
        a0 += __shfl_xor(a0, o); a1 += __shfl_xor(a1, o);
        a2 += __shfl_xor(a2, o); a3 += __shfl_xor(a3, o);
        a4 += __shfl_xor(a4, o); a5 += __shfl_xor(a5, o);
        a6 += __shfl_xor(a6, o); a7 += __shfl_xor(a7, o);
    }

    if (q != 0) return;                        // lanes 0-15 do the stores
    const float inv = 1.f / (dloc + 1e-16f);
    const int f0 = hl * 8;
    float r0 = a0 * inv + bias[f0 + 0], r1 = a1 * inv + bias[f0 + 1];
    float r2 = a2 * inv + bias[f0 + 2], r3 = a3 * inv + bias[f0 + 3];
    float r4 = a4 * inv + bias[f0 + 4], r5 = a5 * inv + bias[f0 + 5];
    float r6 = a6 * inv + bias[f0 + 6], r7 = a7 * inv + bias[f0 + 7];

    float4* outp = reinterpret_cast<float4*>(out + (size_t)d * HD + f0);
    if (mode == 2) {
        float4 o0 = outp[0], o1 = outp[1];
        o0.x = fmaxf(o0.x, r0); o0.y = fmaxf(o0.y, r1);
        o0.z = fmaxf(o0.z, r2); o0.w = fmaxf(o0.w, r3);
        o1.x = fmaxf(o1.x, r4); o1.y = fmaxf(o1.y, r5);
        o1.z = fmaxf(o1.z, r6); o1.w = fmaxf(o1.w, r7);
        outp[0] = o0; outp[1] = o1;
    } else {
        uint4* hp = reinterpret_cast<uint4*>(hb + (size_t)d * HD + f0);
        uint4 hv = *hp;
        float h0 = bf2f((ushort)hv.x), h1 = bf2f((ushort)(hv.x >> 16));
        float h2 = bf2f((ushort)hv.y), h3 = bf2f((ushort)(hv.y >> 16));
        float h4 = bf2f((ushort)hv.z), h5 = bf2f((ushort)(hv.z >> 16));
        float h6 = bf2f((ushort)hv.w), h7 = bf2f((ushort)(hv.w >> 16));
        float n0 = h0 + r0, n1 = h1 + r1, n2 = h2 + r2, n3 = h3 + r3;
        float n4 = h4 + r4, n5 = h5 + r5, n6 = h6 + r6, n7 = h7 + r7;
        uint4 st;
        st.x = (uint32_t)f2bf(n0) | ((uint32_t)f2bf(n1) << 16);
        st.y = (uint32_t)f2bf(n2) | ((uint32_t)f2bf(n3) << 16);
        st.z = (uint32_t)f2bf(n4) | ((uint32_t)f2bf(n5) << 16);
        st.w = (uint32_t)f2bf(n6) | ((uint32_t)f2bf(n7) << 16);
        *hp = st;
        if (mode == 1) {                        // out = max(h1, h2), no out read
            float4 m0, m1;
            m0.x = fmaxf(h0, n0); m0.y = fmaxf(h1, n1);
            m0.z = fmaxf(h2, n2); m0.w = fmaxf(h3, n3);
            m1.x = fmaxf(h4, n4); m1.y = fmaxf(h5, n5);
            m1.z = fmaxf(h6, n6); m1.w = fmaxf(h7, n7);
            outp[0] = m0; outp[1] = m1;
        }
    }
}

// ---------------------------------------------------------------- launch

extern "C" void kernel_launch(void* const* d_in, const int* in_sizes, int n_in,
                              void* d_out, int out_size, void* d_ws, size_t ws_size,
                              hipStream_t stream) {
    const float* x        = (const float*)d_in[0];          // [NN][FIN]
    const int*   ei       = (const int*)d_in[1];            // [2][NE]
    const float* ew       = (const float*)d_in[2];          // [NE]
    /* d_in[3] = numNode scalar = NN */
    const float* Wlin     = (const float*)d_in[4];          // [FIN][HD]
    const float* blin     = (const float*)d_in[5];          // [HD]
    const float* Wc       = (const float*)d_in[6];          // [3][HD][HD]
    const float* att_src  = (const float*)d_in[7];          // [3][HD]
    const float* att_dst  = (const float*)d_in[8];          // [3][HD]
    const float* bias_c   = (const float*)d_in[9];          // [3][HD]
    float* out = (float*)d_out;                              // [NN][HD]

    const int* src = ei;
    const int* dst = ei + NE;

    // workspace layout (16B-aligned blocks, ~37 MB)
    char* w = (char*)d_ws;
    ushort* hb      = (ushort*)w;  w += (size_t)NN * HD * 2;   // h (bf16 residual)
    ushort* hpb     = (ushort*)w;  w += (size_t)NN * HD * 2;   // hp (bf16)
    float*  as_     = (float*)w;   w += (size_t)NN * 4;
    float*  ad_     = (float*)w;   w += (size_t)NN * 4;
    int*    row_ptr = (int*)w;     w += (size_t)(NN + 4) * 4;
    unsigned int* cw = (unsigned int*)w; w += (size_t)NE * 4;  // packed col|bf16(ew)
    uint2*  epk     = (uint2*)w;   w += (size_t)NE * 8;
    int*    bhist   = (int*)w;     w += (size_t)NBK * NCHP * 4;
    int*    bbeg    = (int*)w;     w += (size_t)(NBK + 4) * 4;
    ushort* WTh     = (ushort*)w;  w += (size_t)(HD * FIN + 3 * HD * HD) * 2;
    ushort* WTl     = (ushort*)w;  w += (size_t)(HD * FIN + 3 * HD * HD) * 2;
    ushort* WlinTh = WTh,            *WlinTl = WTl;
    ushort* WcTh   = WTh + HD * FIN, *WcTl   = WTl + HD * FIN;

    const int TB = 256;
    const int nblk_w = (NN * 64 + TB - 1) / TB;      // one wave per node
    const int nblk_g = (NN + 127) / 128;             // 391 (128 rows per block)
    const int nsplit = HD * FIN + 3 * HD * HD;       // all weight elements

    // ---- fused weight transpose + split (1 launch) ----
    k_split_all<<<(nsplit + TB - 1) / TB, TB, 0, stream>>>(Wlin, Wc, WTh, WTl);

    // ---- CSR build (atomic-reservation-free binning) ----
    k_bhist<<<NCH, 1024, 0, stream>>>(dst, bhist);
    k_bscan<<<1, 256, 0, stream>>>(bhist, bbeg, row_ptr);
    k_binscatter<<<NCH, 1024, 0, stream>>>(src, dst, ew, bhist, epk);
    k_build<<<NBK, 256, 0, stream>>>(epk, bbeg, row_ptr, cw);

    // ---- input projection: h = x @ Wlin + blin (bf16 out, fp32 A split) ----
    k_gemm_mfma<FIN, false, false><<<nblk_g, TB, 0, stream>>>(
        x, nullptr, WlinTh, WlinTl, blin, hb,
        nullptr, nullptr, nullptr, nullptr, NN);

    // ---- 3 GAT layers (A = h bf16 exact -> 2-MFMA path) ----
    for (int layer = 0; layer < 3; ++layer) {
        k_gemm_mfma<HD, true, true><<<nblk_g, TB, 0, stream>>>(
            nullptr, hb, WcTh + (size_t)layer * HD * HD, WcTl + (size_t)layer * HD * HD,
            nullptr, hpb,
            att_src + layer * HD, att_dst + layer * HD, as_, ad_, NN);
        int mode = (layer == 0) ? 0 : (layer == 2 ? 2 : 1);
        k_agg<<<nblk_w, TB, 0, stream>>>(hpb, hb, as_, ad_, row_ptr, cw,
                                         bias_c + layer * HD, out, mode);
    }
}

// Round 14
// 219.501 us; speedup vs baseline: 1.7974x; 1.0020x over previous
//
#include <hip/hip_runtime.h>
#include <cstdint>
#include <cstddef>

// Problem constants (from reference)
#define NN 50000
#define NE 800000
#define FIN 256
#define HD 128
#define NEG_SLOPE 0.2f

// CSR-build binning parameters
#define NBK 196          // buckets of 256 nodes: ceil(50000/256)
#define NCH 98           // edge chunks
#define NCHP 104         // padded chunk count (mult of 4 for int4 scan)
#define CHUNK 8192       // edges per chunk (98*8192 >= 800000)

typedef short s16x8 __attribute__((ext_vector_type(8)));   // 8 bf16 (4 VGPRs)
typedef float f32x4 __attribute__((ext_vector_type(4)));   // MFMA accumulator

__device__ inline ushort f2bf(float f) {                   // fp32 -> bf16 RTN-even
    uint32_t u = __float_as_uint(f);
    u += 0x7FFFu + ((u >> 16) & 1u);
    return (ushort)(u >> 16);
}
__device__ inline float bf2f(ushort h) {
    return __uint_as_float(((uint32_t)h) << 16);
}

// ------------------------------------------------------------- CSR build
// bucket = dst >> 8. No global atomics anywhere.
// bhist layout: [bucket][NCHP] (transposed) so the scan kernel loads each
// bucket's row as 26 independent int4s (pipelined) instead of 98 serial
// load/store alternations.

__global__ __launch_bounds__(1024) void k_bhist(const int* __restrict__ dst,
                                                int* __restrict__ bhist) {
    __shared__ int hist[NBK];
    const int tid = threadIdx.x, blk = blockIdx.x;
    if (tid < NBK) hist[tid] = 0;
    __syncthreads();
    const int e0 = blk * CHUNK;
    #pragma unroll
    for (int u = 0; u < CHUNK / 1024; ++u) {
        int e = e0 + u * 1024 + tid;
        if (e < NE) atomicAdd(&hist[dst[e] >> 8], 1);
    }
    __syncthreads();
    if (tid < NBK) {
        bhist[tid * NCHP + blk] = hist[tid];
        if (blk == 0)                          // zero the scan padding once
            for (int c = NCH; c < NCHP; ++c) bhist[tid * NCHP + c] = 0;
    }
}

__global__ __launch_bounds__(256) void k_bscan(int* __restrict__ bhist,
                                               int* __restrict__ bbeg,
                                               int* __restrict__ row_ptr) {
    __shared__ int wsum[4];
    const int tid = threadIdx.x;
    int4 buf[NCHP / 4];
    int tot = 0;
    if (tid < NBK) {
        const int4* rp = reinterpret_cast<const int4*>(bhist + tid * NCHP);
        #pragma unroll
        for (int u = 0; u < NCHP / 4; ++u) buf[u] = rp[u];     // independent loads
        #pragma unroll
        for (int u = 0; u < NCHP / 4; ++u) {                   // exclusive scan in regs
            int4 v = buf[u], o;
            o.x = tot; tot += v.x;
            o.y = tot; tot += v.y;
            o.z = tot; tot += v.z;
            o.w = tot; tot += v.w;
            buf[u] = o;
        }
    }
    const int lane = tid & 63, wid = tid >> 6;
    int x = tot;
    #pragma unroll
    for (int o = 1; o < 64; o <<= 1) {
        int t = __shfl_up(x, o);
        if (lane >= o) x += t;
    }
    if (lane == 63) wsum[wid] = x;
    __syncthreads();
    int wo = 0;
    for (int k = 0; k < wid; ++k) wo += wsum[k];
    const int excl = x - tot + wo;                // bucket start offset
    if (tid < NBK) {
        bbeg[tid] = excl;
        int4* rp = reinterpret_cast<int4*>(bhist + tid * NCHP);
        #pragma unroll
        for (int u = 0; u < NCHP / 4; ++u) {
            int4 v = buf[u];
            v.x += excl; v.y += excl; v.z += excl; v.w += excl;
            rp[u] = v;
        }
    }
    if (tid == 0) { bbeg[NBK] = NE; row_ptr[NN] = NE; }
}

__global__ __launch_bounds__(1024) void k_binscatter(const int* __restrict__ src,
                                                     const int* __restrict__ dst,
                                                     const float* __restrict__ ew,
                                                     const int* __restrict__ bhist,
                                                     uint2* __restrict__ epk) {
    __shared__ int base[NBK];
    __shared__ int lcur[NBK];
    const int tid = threadIdx.x, blk = blockIdx.x;
    if (tid < NBK) { base[tid] = bhist[tid * NCHP + blk]; lcur[tid] = 0; }
    __syncthreads();
    const int e0 = blk * CHUNK;
    #pragma unroll
    for (int u = 0; u < CHUNK / 1024; ++u) {
        int e = e0 + u * 1024 + tid;
        if (e < NE) {
            int d = dst[e];
            int s = src[e];
            float w = ew[e];
            int b = d >> 8;
            int pos = base[b] + atomicAdd(&lcur[b], 1);   // LDS atomic only
            epk[pos] = make_uint2((uint32_t)s | ((uint32_t)(d & 255) << 16),
                                  __float_as_uint(w));
        }
    }
}

__global__ __launch_bounds__(256) void k_build(const uint2* __restrict__ epk,
                                               const int* __restrict__ bbeg,
                                               int* __restrict__ row_ptr,
                                               unsigned int* __restrict__ cw) {
    __shared__ int cnt[256];
    __shared__ int cur[256];
    __shared__ int wsum[4];
    const int tid = threadIdx.x, b = blockIdx.x;
    const int n0 = b << 8;
    const int ebeg = bbeg[b], eend = bbeg[b + 1];
    cnt[tid] = 0;
    __syncthreads();
    for (int e = ebeg + tid; e < eend; e += 256)
        atomicAdd(&cnt[(epk[e].x >> 16) & 255], 1);
    __syncthreads();
    const int v = cnt[tid];
    const int lane = tid & 63, wid = tid >> 6;
    int x = v;
    #pragma unroll
    for (int o = 1; o < 64; o <<= 1) {
        int t = __shfl_up(x, o);
        if (lane >= o) x += t;
    }
    if (lane == 63) wsum[wid] = x;
    __syncthreads();
    int wo = 0;
    for (int k = 0; k < wid; ++k) wo += wsum[k];
    const int excl = ebeg + x - v + wo;           // node segment start
    if (n0 + tid < NN) row_ptr[n0 + tid] = excl;
    cur[tid] = excl;
    __syncthreads();
    for (int e = ebeg + tid; e < eend; e += 256) {
        uint2 p = epk[e];
        int dl = (p.x >> 16) & 255;
        int pos = atomicAdd(&cur[dl], 1);
        // packed edge: low16 = src, high16 = bf16(edge_weight)
        cw[pos] = (p.x & 0xFFFFu) |
                  ((unsigned int)f2bf(__uint_as_float(p.y)) << 16);
    }
}

// -------------------------------------- fused weight transpose + bf16 split
// One launch for all 4 matrices. Wlin [FIN][HD] -> T[HD][FIN] at offset 0;
// Wc[l] [HD][HD] -> T[HD][HD] at offset HD*FIN + l*HD*HD.

__global__ void k_split_all(const float* __restrict__ Wlin,
                            const float* __restrict__ Wc,
                            ushort* __restrict__ Th, ushort* __restrict__ Tl) {
    int idx = blockIdx.x * blockDim.x + threadIdx.x;
    const int NLIN = HD * FIN;
    float f;
    if (idx < NLIN) {
        int n = idx / FIN, k = idx - n * FIN;
        f = Wlin[(size_t)k * HD + n];
    } else if (idx < NLIN + 3 * HD * HD) {
        int r = idx - NLIN;
        int l = r / (HD * HD);
        int rr = r - l * (HD * HD);
        int n = rr / HD, k = rr - n * HD;
        f = Wc[(size_t)l * HD * HD + (size_t)k * HD + n];
    } else return;
    ushort hi = f2bf(f);
    Th[idx] = hi;
    Tl[idx] = f2bf(f - bf2f(hi));
}

// ----------------------------------------------------- MFMA split-bf16 GEMM
// C[M][128] = A[M][K] @ B[K][128] (+bias), 16x16x32 bf16 MFMA, bf16 out.
// ABF16=false: A fp32, split hi/lo in-flight, D = Ah*Bh + Ah*Bl + Al*Bh.
// ABF16=true:  A already bf16 (exact) -> a_l == 0: one 16B A-load and only
//              2 MFMA per col-tile (D = A*Bh + A*Bl).
// B^T hi/lo for a whole BK=128 K-tile staged ONCE into 64 KB LDS
// (XOR-swizzled 16B chunks), barrier-free main loop, 4 waves x 32 rows.

template <int K, bool ATT, bool ABF16>
__global__ __launch_bounds__(256) void k_gemm_mfma(
    const float*  __restrict__ Af,     // fp32 A (ABF16=false)
    const ushort* __restrict__ Ab,     // bf16 A (ABF16=true)
    const ushort* __restrict__ Bh,     // [HD][K]
    const ushort* __restrict__ Bl,     // [HD][K]
    const float*  __restrict__ bias,   // null if none
    ushort*       __restrict__ Cb,     // bf16 out
    const float*  __restrict__ att_s, const float* __restrict__ att_d,
    float* __restrict__ as_, float* __restrict__ ad_,
    int M)
{
    constexpr int BK = 128;                       // K-elems per LDS tile
    constexpr int NT = K / BK;                    // 1 or 2 tiles
    __shared__ ushort Bs[32768];                  // 64 KB: hi [0..16383], lo +16384

    const int tid  = threadIdx.x;
    const int lane = tid & 63;
    const int wid  = tid >> 6;
    const int fl   = lane & 15;                   // A row / B col within frag
    const int fg   = lane >> 4;                   // k-group (8 elems)
    const int rowBase = blockIdx.x * 128 + wid * 32;

    f32x4 acc[2][8] = {};

    for (int t = 0; t < NT; ++t) {
        if (t) __syncthreads();                   // all waves done with tile t-1
        #pragma unroll
        for (int u = 0; u < 8; ++u) {
            const int id  = u * 256 + tid;
            const int bcol = id >> 4, c = id & 15;
            const size_t g = (size_t)bcol * K + t * BK + c * 8;
            const int lidx = bcol * 128 + ((c ^ (bcol & 15)) << 3);
            *reinterpret_cast<uint4*>(&Bs[lidx]) =
                *reinterpret_cast<const uint4*>(Bh + g);
            *reinterpret_cast<uint4*>(&Bs[16384 + lidx]) =
                *reinterpret_cast<const uint4*>(Bl + g);
        }
        __syncthreads();

        #pragma unroll
        for (int kt = 0; kt < BK / 32; ++kt) {
            s16x8 a_h[2], a_l[2];
            #pragma unroll
            for (int rt = 0; rt < 2; ++rt) {
                int r = rowBase + rt * 16 + fl;
                if (r >= M) r = M - 1;            // harmless clamp (stores guarded)
                if (ABF16) {
                    a_h[rt] = *reinterpret_cast<const s16x8*>(
                        Ab + (size_t)r * K + t * BK + kt * 32 + fg * 8);
                } else {
                    const float* ap = Af + (size_t)r * K + t * BK + kt * 32 + fg * 8;
                    float4 t0 = *reinterpret_cast<const float4*>(ap);
                    float4 t1 = *reinterpret_cast<const float4*>(ap + 4);
                    float v[8] = {t0.x, t0.y, t0.z, t0.w, t1.x, t1.y, t1.z, t1.w};
                    #pragma unroll
                    for (int u = 0; u < 8; ++u) {
                        ushort h0 = f2bf(v[u]);
                        a_h[rt][u] = (short)h0;
                        a_l[rt][u] = (short)f2bf(v[u] - bf2f(h0));
                    }
                }
            }
            #pragma unroll
            for (int ct = 0; ct < 8; ++ct) {
                const int lidx = (ct * 16 + fl) * 128 + (((kt * 4 + fg) ^ fl) << 3);
                s16x8 b_h = *reinterpret_cast<const s16x8*>(&Bs[lidx]);
                s16x8 b_l = *reinterpret_cast<const s16x8*>(&Bs[16384 + lidx]);
                #pragma unroll
                for (int rt = 0; rt < 2; ++rt) {
                    acc[rt][ct] = __builtin_amdgcn_mfma_f32_16x16x32_bf16(a_h[rt], b_h, acc[rt][ct], 0, 0, 0);
                    acc[rt][ct] = __builtin_amdgcn_mfma_f32_16x16x32_bf16(a_h[rt], b_l, acc[rt][ct], 0, 0, 0);
                    if (!ABF16)
                        acc[rt][ct] = __builtin_amdgcn_mfma_f32_16x16x32_bf16(a_l[rt], b_h, acc[rt][ct], 0, 0, 0);
                }
            }
        }
    }

    // ---- epilogue: C/D layout col = ct*16 + fl, row = base + fg*4 + reg ----
    float bval[8];
    #pragma unroll
    for (int ct = 0; ct < 8; ++ct) bval[ct] = bias ? bias[ct * 16 + fl] : 0.f;
    float asv[8], adv[8];
    if (ATT) {
        #pragma unroll
        for (int ct = 0; ct < 8; ++ct) {
            asv[ct] = att_s[ct * 16 + fl];
            adv[ct] = att_d[ct * 16 + fl];
        }
    }

    #pragma unroll
    for (int rt = 0; rt < 2; ++rt) {
        const int rbase = rowBase + rt * 16 + fg * 4;
        #pragma unroll
        for (int r = 0; r < 4; ++r) {
            const int row = rbase + r;
            const bool ok = row < M;
            float sv = 0.f, dv = 0.f;
            #pragma unroll
            for (int ct = 0; ct < 8; ++ct) {
                float val = acc[rt][ct][r] + bval[ct];
                if (ATT) { sv = fmaf(val, asv[ct], sv); dv = fmaf(val, adv[ct], dv); }
                if (ok) Cb[(size_t)row * HD + ct * 16 + fl] = f2bf(val);
            }
            if (ATT) {
                #pragma unroll
                for (int o = 1; o < 16; o <<= 1) {    // reduce within 16-lane group
                    sv += __shfl_xor(sv, o);
                    dv += __shfl_xor(dv, o);
                }
                if (fl == 0 && ok) { as_[row] = sv; ad_[row] = dv; }
            }
        }
    }
}

// ---------------------------------------------- fused softmax-aggregation
// One wave per destination node (round-12 structure): lane owns 8 features
// (uint4 = 16 B), 16 lanes cover a row, the 4 wave quarters process 4 edges
// per load instruction (16 edges in flight). Edge metadata is one packed
// uint (col | bf16(ew)<<16). h is stored bf16. No segment-max pass
// (softmax shift-invariant; l clamped 80).
// mode: 0 = h += agg (no out); 1 = out = max(h_old, h_old+agg), h += agg;
// 2 = out = max(out, agg + b).

__global__ __launch_bounds__(256) void k_agg(const ushort* __restrict__ hpb,
                                             ushort* __restrict__ hb,
                                             const float* __restrict__ as_,
                                             const float* __restrict__ ad_,
                                             const int* __restrict__ row_ptr,
                                             const unsigned int* __restrict__ cw,
                                             const float* __restrict__ bias,
                                             float* __restrict__ out, int mode) {
    int wave = (blockIdx.x * blockDim.x + threadIdx.x) >> 6;
    int lane = threadIdx.x & 63;
    if (wave >= NN) return;
    const int d = wave;
    const int beg = row_ptr[d], end = row_ptr[d + 1];
    const float adv = ad_[d];
    const int q  = lane >> 4;          // which of 4 concurrent edges
    const int hl = lane & 15;          // feature octet: owns [hl*8, hl*8+8)

    float a0 = 0.f, a1 = 0.f, a2 = 0.f, a3 = 0.f;
    float a4 = 0.f, a5 = 0.f, a6 = 0.f, a7 = 0.f, dloc = 0.f;

    for (int base = beg; base < end; base += 64) {
        const int n = min(64, end - base);
        int s = 0; float w = 0.f;
        if (lane < n) {
            unsigned int v = cw[base + lane];
            s = (int)(v & 0xFFFFu);
            float l = as_[s] + adv;
            l = (l >= 0.f) ? l : NEG_SLOPE * l;
            l = fminf(l, 80.f);                    // overflow guard (no max pass)
            w = __expf(l) * bf2f((ushort)(v >> 16));
        }
        dloc += w;

        int i = 0;
        for (; i + 15 < n; i += 16) {          // 16 edges = 4 quad loads in flight
            float wv[4]; int sv[4]; uint4 pv[4];
            #pragma unroll
            for (int j = 0; j < 4; ++j) {
                const int idx = i + 4 * j + q;
                wv[j] = __shfl(w, idx);
                sv[j] = __shfl(s, idx);
            }
            #pragma unroll
            for (int j = 0; j < 4; ++j)
                pv[j] = *reinterpret_cast<const uint4*>(hpb + (size_t)sv[j] * HD + hl * 8);
            #pragma unroll
            for (int j = 0; j < 4; ++j) {
                a0 = fmaf(wv[j], bf2f((ushort)pv[j].x),         a0);
                a1 = fmaf(wv[j], bf2f((ushort)(pv[j].x >> 16)), a1);
                a2 = fmaf(wv[j], bf2f((ushort)pv[j].y),         a2);
                a3 = fmaf(wv[j], bf2f((ushort)(pv[j].y >> 16)), a3);
                a4 = fmaf(wv[j], bf2f((ushort)pv[j].z),         a4);
                a5 = fmaf(wv[j], bf2f((ushort)(pv[j].z >> 16)), a5);
                a6 = fmaf(wv[j], bf2f((ushort)pv[j].w),         a6);
                a7 = fmaf(wv[j], bf2f((ushort)(pv[j].w >> 16)), a7);
            }
        }
        for (; i + 3 < n; i += 4) {            // 4-edge steps
            const int idx = i + q;
            float wj = __shfl(w, idx);
            int   sj = __shfl(s, idx);
            uint4 pv = *reinterpret_cast<const uint4*>(hpb + (size_t)sj * HD + hl * 8);
            a0 = fmaf(wj, bf2f((ushort)pv.x),         a0);
            a1 = fmaf(wj, bf2f((ushort)(pv.x >> 16)), a1);
            a2 = fmaf(wj, bf2f((ushort)pv.y),         a2);
            a3 = fmaf(wj, bf2f((ushort)(pv.y >> 16)), a3);
            a4 = fmaf(wj, bf2f((ushort)pv.z),         a4);
            a5 = fmaf(wj, bf2f((ushort)(pv.z >> 16)), a5);
            a6 = fmaf(wj, bf2f((ushort)pv.w),         a6);
            a7 = fmaf(wj, bf2f((ushort)(pv.w >> 16)), a7);
        }
        if (i < n) {                           // tail < 4 edges (masked)
            const int e = i + q;
            const bool ok = e < n;
            const int idx = ok ? e : i;
            float wj = __shfl(w, idx);
            int   sj = __shfl(s, idx);
            if (!ok) wj = 0.f;
            uint4 pv = *reinterpret_cast<const uint4*>(hpb + (size_t)sj * HD + hl * 8);
            a0 = fmaf(wj, bf2f((ushort)pv.x),         a0);
            a1 = fmaf(wj, bf2f((ushort)(pv.x >> 16)), a1);
            a2 = fmaf(wj, bf2f((ushort)pv.y),         a2);
            a3 = fmaf(wj, bf2f((ushort)(pv.y >> 16)), a3);
            a4 = fmaf(wj, bf2f((ushort)pv.z),         a4);
            a5 = fmaf(wj, bf2f((ushort)(pv.z >> 16)), a5);
            a6 = fmaf(wj, bf2f((ushort)pv.w),         a6);
            a7 = fmaf(wj, bf2f((ushort)(pv.w >> 16)), a7);
        }
    }
    #pragma unroll
    for (int o = 32; o > 0; o >>= 1) dloc += __shfl_xor(dloc, o);
    #pragma unroll
    for (int o = 32; o >= 16; o >>= 1) {
        a0 += __shfl_xor(a0, o); a1 += __shfl_xor(a1, o);
        a2 += __shfl_xor(a2, o); a3 += __shfl_xor(a3, o);
        a4 += __shfl_xor(a4, o); a5 += __shfl_xor(a5, o);
        a6 += __shfl_xor(a6, o); a7 += __shfl_xor(a7, o);
    }

    if (q != 0) return;                        // lanes 0-15 do the stores
    const float inv = 1.f / (dloc + 1e-16f);
    const int f0 = hl * 8;
    float r0 = a0 * inv + bias[f0 + 0], r1 = a1 * inv + bias[f0 + 1];
    float r2 = a2 * inv + bias[f0 + 2], r3 = a3 * inv + bias[f0 + 3];
    float r4 = a4 * inv + bias[f0 + 4], r5 = a5 * inv + bias[f0 + 5];
    float r6 = a6 * inv + bias[f0 + 6], r7 = a7 * inv + bias[f0 + 7];

    float4* outp = reinterpret_cast<float4*>(out + (size_t)d * HD + f0);
    if (mode == 2) {
        float4 o0 = outp[0], o1 = outp[1];
        o0.x = fmaxf(o0.x, r0); o0.y = fmaxf(o0.y, r1);
        o0.z = fmaxf(o0.z, r2); o0.w = fmaxf(o0.w, r3);
        o1.x = fmaxf(o1.x, r4); o1.y = fmaxf(o1.y, r5);
        o1.z = fmaxf(o1.z, r6); o1.w = fmaxf(o1.w, r7);
        outp[0] = o0; outp[1] = o1;
    } else {
        uint4* hp = reinterpret_cast<uint4*>(hb + (size_t)d * HD + f0);
        uint4 hv = *hp;
        float h0 = bf2f((ushort)hv.x), h1 = bf2f((ushort)(hv.x >> 16));
        float h2 = bf2f((ushort)hv.y), h3 = bf2f((ushort)(hv.y >> 16));
        float h4 = bf2f((ushort)hv.z), h5 = bf2f((ushort)(hv.z >> 16));
        float h6 = bf2f((ushort)hv.w), h7 = bf2f((ushort)(hv.w >> 16));
        float n0 = h0 + r0, n1 = h1 + r1, n2 = h2 + r2, n3 = h3 + r3;
        float n4 = h4 + r4, n5 = h5 + r5, n6 = h6 + r6, n7 = h7 + r7;
        uint4 st;
        st.x = (uint32_t)f2bf(n0) | ((uint32_t)f2bf(n1) << 16);
        st.y = (uint32_t)f2bf(n2) | ((uint32_t)f2bf(n3) << 16);
        st.z = (uint32_t)f2bf(n4) | ((uint32_t)f2bf(n5) << 16);
        st.w = (uint32_t)f2bf(n6) | ((uint32_t)f2bf(n7) << 16);
        *hp = st;
        if (mode == 1) {                        // out = max(h1, h2), no out read
            float4 m0, m1;
            m0.x = fmaxf(h0, n0); m0.y = fmaxf(h1, n1);
            m0.z = fmaxf(h2, n2); m0.w = fmaxf(h3, n3);
            m1.x = fmaxf(h4, n4); m1.y = fmaxf(h5, n5);
            m1.z = fmaxf(h6, n6); m1.w = fmaxf(h7, n7);
            outp[0] = m0; outp[1] = m1;
        }
    }
}

// ---------------------------------------------------------------- launch

extern "C" void kernel_launch(void* const* d_in, const int* in_sizes, int n_in,
                              void* d_out, int out_size, void* d_ws, size_t ws_size,
                              hipStream_t stream) {
    const float* x        = (const float*)d_in[0];          // [NN][FIN]
    const int*   ei       = (const int*)d_in[1];            // [2][NE]
    const float* ew       = (const float*)d_in[2];          // [NE]
    /* d_in[3] = numNode scalar = NN */
    const float* Wlin     = (const float*)d_in[4];          // [FIN][HD]
    const float* blin     = (const float*)d_in[5];          // [HD]
    const float* Wc       = (const float*)d_in[6];          // [3][HD][HD]
    const float* att_src  = (const float*)d_in[7];          // [3][HD]
    const float* att_dst  = (const float*)d_in[8];          // [3][HD]
    const float* bias_c   = (const float*)d_in[9];          // [3][HD]
    float* out = (float*)d_out;                              // [NN][HD]

    const int* src = ei;
    const int* dst = ei + NE;

    // workspace layout (16B-aligned blocks, ~37 MB)
    char* w = (char*)d_ws;
    ushort* hb      = (ushort*)w;  w += (size_t)NN * HD * 2;   // h (bf16 residual)
    ushort* hpb     = (ushort*)w;  w += (size_t)NN * HD * 2;   // hp (bf16)
    float*  as_     = (float*)w;   w += (size_t)NN * 4;
    float*  ad_     = (float*)w;   w += (size_t)NN * 4;
    int*    row_ptr = (int*)w;     w += (size_t)(NN + 4) * 4;
    unsigned int* cw = (unsigned int*)w; w += (size_t)NE * 4;  // packed col|bf16(ew)
    uint2*  epk     = (uint2*)w;   w += (size_t)NE * 8;
    int*    bhist   = (int*)w;     w += (size_t)NBK * NCHP * 4;
    int*    bbeg    = (int*)w;     w += (size_t)(NBK + 4) * 4;
    ushort* WTh     = (ushort*)w;  w += (size_t)(HD * FIN + 3 * HD * HD) * 2;
    ushort* WTl     = (ushort*)w;  w += (size_t)(HD * FIN + 3 * HD * HD) * 2;
    ushort* WlinTh = WTh,            *WlinTl = WTl;
    ushort* WcTh   = WTh + HD * FIN, *WcTl   = WTl + HD * FIN;

    const int TB = 256;
    const int nblk_w = (NN * 64 + TB - 1) / TB;      // one wave per node
    const int nblk_g = (NN + 127) / 128;             // 391 (128 rows per block)
    const int nsplit = HD * FIN + 3 * HD * HD;       // all weight elements

    // ---- fused weight transpose + split (1 launch) ----
    k_split_all<<<(nsplit + TB - 1) / TB, TB, 0, stream>>>(Wlin, Wc, WTh, WTl);

    // ---- CSR build (atomic-reservation-free binning) ----
    k_bhist<<<NCH, 1024, 0, stream>>>(dst, bhist);
    k_bscan<<<1, 256, 0, stream>>>(bhist, bbeg, row_ptr);
    k_binscatter<<<NCH, 1024, 0, stream>>>(src, dst, ew, bhist, epk);
    k_build<<<NBK, 256, 0, stream>>>(epk, bbeg, row_ptr, cw);

    // ---- input projection: h = x @ Wlin + blin (bf16 out, fp32 A split) ----
    k_gemm_mfma<FIN, false, false><<<nblk_g, TB, 0, stream>>>(
        x, nullptr, WlinTh, WlinTl, blin, hb,
        nullptr, nullptr, nullptr, nullptr, NN);

    // ---- 3 GAT layers (A = h bf16 exact -> 2-MFMA path) ----
    for (int layer = 0; layer < 3; ++layer) {
        k_gemm_mfma<HD, true, true><<<nblk_g, TB, 0, stream>>>(
            nullptr, hb, WcTh + (size_t)layer * HD * HD, WcTl + (size_t)layer * HD * HD,
            nullptr, hpb,
            att_src + layer * HD, att_dst + layer * HD, as_, ad_, NN);
        int mode = (layer == 0) ? 0 : (layer == 2 ? 2 : 1);
        k_agg<<<nblk_w, TB, 0, stream>>>(hpb, hb, as_, ad_, row_ptr, cw,
                                         bias_c + layer * HD, out, mode);
    }
}

// Round 15
// 210.120 us; speedup vs baseline: 1.8777x; 1.0446x over previous
//
#include <hip/hip_runtime.h>
#include <cstdint>
#include <cstddef>

// Problem constants (from reference)
#define NN 50000
#define NE 800000
#define FIN 256
#define HD 128
#define NEG_SLOPE 0.2f

// CSR-build binning parameters
#define NBK 196          // buckets of 256 nodes: ceil(50000/256)
#define NCH 98           // edge chunks
#define NCHP 104         // padded chunk count (mult of 4 for int4 scan)
#define CHUNK 8192       // edges per chunk (98*8192 >= 800000)

typedef short s16x8 __attribute__((ext_vector_type(8)));   // 8 bf16 (4 VGPRs)
typedef float f32x4 __attribute__((ext_vector_type(4)));   // MFMA accumulator

__device__ inline ushort f2bf(float f) {                   // fp32 -> bf16 RTN-even
    uint32_t u = __float_as_uint(f);
    u += 0x7FFFu + ((u >> 16) & 1u);
    return (ushort)(u >> 16);
}
__device__ inline float bf2f(ushort h) {
    return __uint_as_float(((uint32_t)h) << 16);
}

// ------------------------------------------------------------- CSR build
// bucket = dst >> 8. No global atomics anywhere.

__global__ __launch_bounds__(1024) void k_bhist(const int* __restrict__ dst,
                                                int* __restrict__ bhist) {
    __shared__ int hist[NBK];
    const int tid = threadIdx.x, blk = blockIdx.x;
    if (tid < NBK) hist[tid] = 0;
    __syncthreads();
    const int e0 = blk * CHUNK;
    #pragma unroll
    for (int u = 0; u < CHUNK / 1024; ++u) {
        int e = e0 + u * 1024 + tid;
        if (e < NE) atomicAdd(&hist[dst[e] >> 8], 1);
    }
    __syncthreads();
    if (tid < NBK) {
        bhist[tid * NCHP + blk] = hist[tid];
        if (blk == 0)                          // zero the scan padding once
            for (int c = NCH; c < NCHP; ++c) bhist[tid * NCHP + c] = 0;
    }
}

__global__ __launch_bounds__(256) void k_bscan(int* __restrict__ bhist,
                                               int* __restrict__ bbeg,
                                               int* __restrict__ row_ptr) {
    __shared__ int wsum[4];
    const int tid = threadIdx.x;
    int4 buf[NCHP / 4];
    int tot = 0;
    if (tid < NBK) {
        const int4* rp = reinterpret_cast<const int4*>(bhist + tid * NCHP);
        #pragma unroll
        for (int u = 0; u < NCHP / 4; ++u) buf[u] = rp[u];     // independent loads
        #pragma unroll
        for (int u = 0; u < NCHP / 4; ++u) {                   // exclusive scan in regs
            int4 v = buf[u], o;
            o.x = tot; tot += v.x;
            o.y = tot; tot += v.y;
            o.z = tot; tot += v.z;
            o.w = tot; tot += v.w;
            buf[u] = o;
        }
    }
    const int lane = tid & 63, wid = tid >> 6;
    int x = tot;
    #pragma unroll
    for (int o = 1; o < 64; o <<= 1) {
        int t = __shfl_up(x, o);
        if (lane >= o) x += t;
    }
    if (lane == 63) wsum[wid] = x;
    __syncthreads();
    int wo = 0;
    for (int k = 0; k < wid; ++k) wo += wsum[k];
    const int excl = x - tot + wo;                // bucket start offset
    if (tid < NBK) {
        bbeg[tid] = excl;
        int4* rp = reinterpret_cast<int4*>(bhist + tid * NCHP);
        #pragma unroll
        for (int u = 0; u < NCHP / 4; ++u) {
            int4 v = buf[u];
            v.x += excl; v.y += excl; v.z += excl; v.w += excl;
            rp[u] = v;
        }
    }
    if (tid == 0) { bbeg[NBK] = NE; row_ptr[NN] = NE; }
}

__global__ __launch_bounds__(1024) void k_binscatter(const int* __restrict__ src,
                                                     const int* __restrict__ dst,
                                                     const float* __restrict__ ew,
                                                     const int* __restrict__ bhist,
                                                     uint2* __restrict__ epk) {
    __shared__ int base[NBK];
    __shared__ int lcur[NBK];
    const int tid = threadIdx.x, blk = blockIdx.x;
    if (tid < NBK) { base[tid] = bhist[tid * NCHP + blk]; lcur[tid] = 0; }
    __syncthreads();
    const int e0 = blk * CHUNK;
    #pragma unroll
    for (int u = 0; u < CHUNK / 1024; ++u) {
        int e = e0 + u * 1024 + tid;
        if (e < NE) {
            int d = dst[e];
            int s = src[e];
            float w = ew[e];
            int b = d >> 8;
            int pos = base[b] + atomicAdd(&lcur[b], 1);   // LDS atomic only
            epk[pos] = make_uint2((uint32_t)s | ((uint32_t)(d & 255) << 16),
                                  __float_as_uint(w));
        }
    }
}

__global__ __launch_bounds__(256) void k_build(const uint2* __restrict__ epk,
                                               const int* __restrict__ bbeg,
                                               int* __restrict__ row_ptr,
                                               unsigned int* __restrict__ cw) {
    __shared__ int cnt[256];
    __shared__ int cur[256];
    __shared__ int wsum[4];
    const int tid = threadIdx.x, b = blockIdx.x;
    const int n0 = b << 8;
    const int ebeg = bbeg[b], eend = bbeg[b + 1];
    cnt[tid] = 0;
    __syncthreads();
    for (int e = ebeg + tid; e < eend; e += 256)
        atomicAdd(&cnt[(epk[e].x >> 16) & 255], 1);
    __syncthreads();
    const int v = cnt[tid];
    const int lane = tid & 63, wid = tid >> 6;
    int x = v;
    #pragma unroll
    for (int o = 1; o < 64; o <<= 1) {
        int t = __shfl_up(x, o);
        if (lane >= o) x += t;
    }
    if (lane == 63) wsum[wid] = x;
    __syncthreads();
    int wo = 0;
    for (int k = 0; k < wid; ++k) wo += wsum[k];
    const int excl = ebeg + x - v + wo;           // node segment start
    if (n0 + tid < NN) row_ptr[n0 + tid] = excl;
    cur[tid] = excl;
    __syncthreads();
    for (int e = ebeg + tid; e < eend; e += 256) {
        uint2 p = epk[e];
        int dl = (p.x >> 16) & 255;
        int pos = atomicAdd(&cur[dl], 1);
        // packed edge: low16 = src, high16 = bf16(edge_weight)
        cw[pos] = (p.x & 0xFFFFu) |
                  ((unsigned int)f2bf(__uint_as_float(p.y)) << 16);
    }
}

// -------------------------------------- fused weight transpose + bf16 split

__global__ void k_split_all(const float* __restrict__ Wlin,
                            const float* __restrict__ Wc,
                            ushort* __restrict__ Th, ushort* __restrict__ Tl) {
    int idx = blockIdx.x * blockDim.x + threadIdx.x;
    const int NLIN = HD * FIN;
    float f;
    if (idx < NLIN) {
        int n = idx / FIN, k = idx - n * FIN;
        f = Wlin[(size_t)k * HD + n];
    } else if (idx < NLIN + 3 * HD * HD) {
        int r = idx - NLIN;
        int l = r / (HD * HD);
        int rr = r - l * (HD * HD);
        int n = rr / HD, k = rr - n * HD;
        f = Wc[(size_t)l * HD * HD + (size_t)k * HD + n];
    } else return;
    ushort hi = f2bf(f);
    Th[idx] = hi;
    Tl[idx] = f2bf(f - bf2f(hi));
}

// ----------------------------------------------------- MFMA split-bf16 GEMM
// C[M][128] = A[M][K] @ B[K][128] (+bias), 16x16x32 bf16 MFMA.
// ABF16=false: A fp32, split hi/lo in-flight (3 MFMA). ABF16=true: A bf16
// exact (2 MFMA). OUT8=false: bf16 out. OUT8=true: int8 per-row-scaled out
// (q = rint(val*127/rowmax)) + sig[row] = rowmax/127; as_/ad_ from exact vals.
// B^T hi/lo whole-BK=128 K-tile staged once into 64 KB LDS (XOR-swizzled),
// barrier-free main loop, 4 waves x 32 rows, grid 391.

template <int K, bool ATT, bool ABF16, bool OUT8>
__global__ __launch_bounds__(256) void k_gemm_mfma(
    const float*  __restrict__ Af,     // fp32 A (ABF16=false)
    const ushort* __restrict__ Ab,     // bf16 A (ABF16=true)
    const ushort* __restrict__ Bh,     // [HD][K]
    const ushort* __restrict__ Bl,     // [HD][K]
    const float*  __restrict__ bias,   // null if none
    ushort*       __restrict__ Cb,     // bf16 out (OUT8=false)
    signed char*  __restrict__ C8,     // int8 out (OUT8=true)
    float*        __restrict__ sig,    // per-row scale (OUT8=true)
    const float*  __restrict__ att_s, const float* __restrict__ att_d,
    float* __restrict__ as_, float* __restrict__ ad_,
    int M)
{
    constexpr int BK = 128;
    constexpr int NT = K / BK;
    __shared__ ushort Bs[32768];                  // 64 KB: hi [0..16383], lo +16384

    const int tid  = threadIdx.x;
    const int lane = tid & 63;
    const int wid  = tid >> 6;
    const int fl   = lane & 15;
    const int fg   = lane >> 4;
    const int rowBase = blockIdx.x * 128 + wid * 32;

    f32x4 acc[2][8] = {};

    for (int t = 0; t < NT; ++t) {
        if (t) __syncthreads();
        #pragma unroll
        for (int u = 0; u < 8; ++u) {
            const int id  = u * 256 + tid;
            const int bcol = id >> 4, c = id & 15;
            const size_t g = (size_t)bcol * K + t * BK + c * 8;
            const int lidx = bcol * 128 + ((c ^ (bcol & 15)) << 3);
            *reinterpret_cast<uint4*>(&Bs[lidx]) =
                *reinterpret_cast<const uint4*>(Bh + g);
            *reinterpret_cast<uint4*>(&Bs[16384 + lidx]) =
                *reinterpret_cast<const uint4*>(Bl + g);
        }
        __syncthreads();

        #pragma unroll
        for (int kt = 0; kt < BK / 32; ++kt) {
            s16x8 a_h[2], a_l[2];
            #pragma unroll
            for (int rt = 0; rt < 2; ++rt) {
                int r = rowBase + rt * 16 + fl;
                if (r >= M) r = M - 1;            // harmless clamp (stores guarded)
                if (ABF16) {
                    a_h[rt] = *reinterpret_cast<const s16x8*>(
                        Ab + (size_t)r * K + t * BK + kt * 32 + fg * 8);
                } else {
                    const float* ap = Af + (size_t)r * K + t * BK + kt * 32 + fg * 8;
                    float4 t0 = *reinterpret_cast<const float4*>(ap);
                    float4 t1 = *reinterpret_cast<const float4*>(ap + 4);
                    float v[8] = {t0.x, t0.y, t0.z, t0.w, t1.x, t1.y, t1.z, t1.w};
                    #pragma unroll
                    for (int u = 0; u < 8; ++u) {
                        ushort h0 = f2bf(v[u]);
                        a_h[rt][u] = (short)h0;
                        a_l[rt][u] = (short)f2bf(v[u] - bf2f(h0));
                    }
                }
            }
            #pragma unroll
            for (int ct = 0; ct < 8; ++ct) {
                const int lidx = (ct * 16 + fl) * 128 + (((kt * 4 + fg) ^ fl) << 3);
                s16x8 b_h = *reinterpret_cast<const s16x8*>(&Bs[lidx]);
                s16x8 b_l = *reinterpret_cast<const s16x8*>(&Bs[16384 + lidx]);
                #pragma unroll
                for (int rt = 0; rt < 2; ++rt) {
                    acc[rt][ct] = __builtin_amdgcn_mfma_f32_16x16x32_bf16(a_h[rt], b_h, acc[rt][ct], 0, 0, 0);
                    acc[rt][ct] = __builtin_amdgcn_mfma_f32_16x16x32_bf16(a_h[rt], b_l, acc[rt][ct], 0, 0, 0);
                    if (!ABF16)
                        acc[rt][ct] = __builtin_amdgcn_mfma_f32_16x16x32_bf16(a_l[rt], b_h, acc[rt][ct], 0, 0, 0);
                }
            }
        }
    }

    // ---- epilogue: C/D layout col = ct*16 + fl, row = base + fg*4 + reg ----
    float bval[8];
    #pragma unroll
    for (int ct = 0; ct < 8; ++ct) bval[ct] = bias ? bias[ct * 16 + fl] : 0.f;
    float asv[8], adv[8];
    if (ATT) {
        #pragma unroll
        for (int ct = 0; ct < 8; ++ct) {
            asv[ct] = att_s[ct * 16 + fl];
            adv[ct] = att_d[ct * 16 + fl];
        }
    }

    #pragma unroll
    for (int rt = 0; rt < 2; ++rt) {
        const int rbase = rowBase + rt * 16 + fg * 4;
        #pragma unroll
        for (int r = 0; r < 4; ++r) {
            const int row = rbase + r;
            const bool ok = row < M;
            float sv = 0.f, dv = 0.f, m = 0.f;
            float val[8];
            #pragma unroll
            for (int ct = 0; ct < 8; ++ct) {
                val[ct] = acc[rt][ct][r] + bval[ct];
                if (ATT) { sv = fmaf(val[ct], asv[ct], sv); dv = fmaf(val[ct], adv[ct], dv); }
                if (OUT8) m = fmaxf(m, fabsf(val[ct]));
            }
            if (OUT8) {
                #pragma unroll
                for (int o = 1; o < 16; o <<= 1) m = fmaxf(m, __shfl_xor(m, o));
                const float qs = 127.f / fmaxf(m, 1e-30f);
                #pragma unroll
                for (int ct = 0; ct < 8; ++ct) {
                    int qv = (int)rintf(val[ct] * qs);
                    qv = qv < -127 ? -127 : (qv > 127 ? 127 : qv);
                    if (ok) C8[(size_t)row * HD + ct * 16 + fl] = (signed char)qv;
                }
                if (fl == 0 && ok) sig[row] = m * (1.f / 127.f);
            } else {
                #pragma unroll
                for (int ct = 0; ct < 8; ++ct)
                    if (ok) Cb[(size_t)row * HD + ct * 16 + fl] = f2bf(val[ct]);
            }
            if (ATT) {
                #pragma unroll
                for (int o = 1; o < 16; o <<= 1) {
                    sv += __shfl_xor(sv, o);
                    dv += __shfl_xor(dv, o);
                }
                if (fl == 0 && ok) { as_[row] = sv; ad_[row] = dv; }
            }
        }
    }
}

// ---------------------------------------------- fused softmax-aggregation
// One wave per node. hp is int8 per-row-scaled (128 B/row); the row scale is
// folded into the broadcast weight (we = w * sig[src]); denominator uses raw
// w, so softmax semantics are exact. Lane owns 8 features (uint2 = 8 B int8),
// 16 lanes/row, 4 wave quarters process 4 edges per load (16 edges in
// flight). h residual bf16. No segment-max pass (shift-invariant; l<=80).
// mode 0: h += agg (no out). mode 1: mx = bf16(max(h_old, h_new)), h += agg.
// mode 2: out = max(bf2f(mx), agg + b)  (write-only out).

__device__ inline void acc8(float wj, uint2 pv,
                            float& a0, float& a1, float& a2, float& a3,
                            float& a4, float& a5, float& a6, float& a7) {
    a0 = fmaf(wj, (float)(int)(signed char)(pv.x       ), a0);
    a1 = fmaf(wj, (float)(int)(signed char)(pv.x >>  8 ), a1);
    a2 = fmaf(wj, (float)(int)(signed char)(pv.x >> 16 ), a2);
    a3 = fmaf(wj, (float)(int)(signed char)(pv.x >> 24 ), a3);
    a4 = fmaf(wj, (float)(int)(signed char)(pv.y       ), a4);
    a5 = fmaf(wj, (float)(int)(signed char)(pv.y >>  8 ), a5);
    a6 = fmaf(wj, (float)(int)(signed char)(pv.y >> 16 ), a6);
    a7 = fmaf(wj, (float)(int)(signed char)(pv.y >> 24 ), a7);
}

__global__ __launch_bounds__(256) void k_agg(const signed char* __restrict__ hp8,
                                             const float* __restrict__ sig,
                                             ushort* __restrict__ hb,
                                             const float* __restrict__ as_,
                                             const float* __restrict__ ad_,
                                             const int* __restrict__ row_ptr,
                                             const unsigned int* __restrict__ cw,
                                             const float* __restrict__ bias,
                                             float* __restrict__ out,
                                             ushort* __restrict__ mx, int mode) {
    int wave = (blockIdx.x * blockDim.x + threadIdx.x) >> 6;
    int lane = threadIdx.x & 63;
    if (wave >= NN) return;
    const int d = wave;
    const int beg = row_ptr[d], end = row_ptr[d + 1];
    const float adv = ad_[d];
    const int q  = lane >> 4;          // which of 4 concurrent edges
    const int hl = lane & 15;          // feature octet: owns [hl*8, hl*8+8)

    float a0 = 0.f, a1 = 0.f, a2 = 0.f, a3 = 0.f;
    float a4 = 0.f, a5 = 0.f, a6 = 0.f, a7 = 0.f, dloc = 0.f;

    for (int base = beg; base < end; base += 64) {
        const int n = min(64, end - base);
        int s = 0; float w = 0.f, we = 0.f;
        if (lane < n) {
            unsigned int v = cw[base + lane];
            s = (int)(v & 0xFFFFu);
            float l = as_[s] + adv;
            l = (l >= 0.f) ? l : NEG_SLOPE * l;
            l = fminf(l, 80.f);                    // overflow guard (no max pass)
            w  = __expf(l) * bf2f((ushort)(v >> 16));
            we = w * sig[s];                       // fold row scale into weight
        }
        dloc += w;

        int i = 0;
        for (; i + 15 < n; i += 16) {          // 16 edges = 4 quad loads in flight
            float wv[4]; int sv[4]; uint2 pv[4];
            #pragma unroll
            for (int j = 0; j < 4; ++j) {
                const int idx = i + 4 * j + q;
                wv[j] = __shfl(we, idx);
                sv[j] = __shfl(s,  idx);
            }
            #pragma unroll
            for (int j = 0; j < 4; ++j)
                pv[j] = *reinterpret_cast<const uint2*>(hp8 + (size_t)sv[j] * HD + hl * 8);
            #pragma unroll
            for (int j = 0; j < 4; ++j)
                acc8(wv[j], pv[j], a0, a1, a2, a3, a4, a5, a6, a7);
        }
        for (; i + 3 < n; i += 4) {            // 4-edge steps
            const int idx = i + q;
            float wj = __shfl(we, idx);
            int   sj = __shfl(s,  idx);
            uint2 pv = *reinterpret_cast<const uint2*>(hp8 + (size_t)sj * HD + hl * 8);
            acc8(wj, pv, a0, a1, a2, a3, a4, a5, a6, a7);
        }
        if (i < n) {                           // tail < 4 edges (masked)
            const int e = i + q;
            const bool ok = e < n;
            const int idx = ok ? e : i;
            float wj = __shfl(we, idx);
            int   sj = __shfl(s,  idx);
            if (!ok) wj = 0.f;
            uint2 pv = *reinterpret_cast<const uint2*>(hp8 + (size_t)sj * HD + hl * 8);
            acc8(wj, pv, a0, a1, a2, a3, a4, a5, a6, a7);
        }
    }
    #pragma unroll
    for (int o = 32; o > 0; o >>= 1) dloc += __shfl_xor(dloc, o);
    #pragma unroll
    for (int o = 32; o >= 16; o >>= 1) {
        a0 += __shfl_xor(a0, o); a1 += __shfl_xor(a1, o);
        a2 += __shfl_xor(a2, o); a3 += __shfl_xor(a3, o);
        a4 += __shfl_xor(a4, o); a5 += __shfl_xor(a5, o);
        a6 += __shfl_xor(a6, o); a7 += __shfl_xor(a7, o);
    }

    if (q != 0) return;                        // lanes 0-15 do the stores
    const float inv = 1.f / (dloc + 1e-16f);
    const int f0 = hl * 8;
    float r0 = a0 * inv + bias[f0 + 0], r1 = a1 * inv + bias[f0 + 1];
    float r2 = a2 * inv + bias[f0 + 2], r3 = a3 * inv + bias[f0 + 3];
    float r4 = a4 * inv + bias[f0 + 4], r5 = a5 * inv + bias[f0 + 5];
    float r6 = a6 * inv + bias[f0 + 6], r7 = a7 * inv + bias[f0 + 7];

    if (mode == 2) {
        uint4 mv = *reinterpret_cast<const uint4*>(mx + (size_t)d * HD + f0);
        float4 o0, o1;
        o0.x = fmaxf(bf2f((ushort)mv.x),         r0);
        o0.y = fmaxf(bf2f((ushort)(mv.x >> 16)), r1);
        o0.z = fmaxf(bf2f((ushort)mv.y),         r2);
        o0.w = fmaxf(bf2f((ushort)(mv.y >> 16)), r3);
        o1.x = fmaxf(bf2f((ushort)mv.z),         r4);
        o1.y = fmaxf(bf2f((ushort)(mv.z >> 16)), r5);
        o1.z = fmaxf(bf2f((ushort)mv.w),         r6);
        o1.w = fmaxf(bf2f((ushort)(mv.w >> 16)), r7);
        float4* outp = reinterpret_cast<float4*>(out + (size_t)d * HD + f0);
        outp[0] = o0; outp[1] = o1;            // write-only full overwrite
    } else {
        uint4* hp = reinterpret_cast<uint4*>(hb + (size_t)d * HD + f0);
        uint4 hv = *hp;
        float h0 = bf2f((ushort)hv.x), h1 = bf2f((ushort)(hv.x >> 16));
        float h2 = bf2f((ushort)hv.y), h3 = bf2f((ushort)(hv.y >> 16));
        float h4 = bf2f((ushort)hv.z), h5 = bf2f((ushort)(hv.z >> 16));
        float h6 = bf2f((ushort)hv.w), h7 = bf2f((ushort)(hv.w >> 16));
        float n0 = h0 + r0, n1 = h1 + r1, n2 = h2 + r2, n3 = h3 + r3;
        float n4 = h4 + r4, n5 = h5 + r5, n6 = h6 + r6, n7 = h7 + r7;
        uint4 st;
        st.x = (uint32_t)f2bf(n0) | ((uint32_t)f2bf(n1) << 16);
        st.y = (uint32_t)f2bf(n2) | ((uint32_t)f2bf(n3) << 16);
        st.z = (uint32_t)f2bf(n4) | ((uint32_t)f2bf(n5) << 16);
        st.w = (uint32_t)f2bf(n6) | ((uint32_t)f2bf(n7) << 16);
        *hp = st;
        if (mode == 1) {                        // mx = bf16(max(h1, h2))
            uint4 sm;
            sm.x = (uint32_t)f2bf(fmaxf(h0, n0)) | ((uint32_t)f2bf(fmaxf(h1, n1)) << 16);
            sm.y = (uint32_t)f2bf(fmaxf(h2, n2)) | ((uint32_t)f2bf(fmaxf(h3, n3)) << 16);
            sm.z = (uint32_t)f2bf(fmaxf(h4, n4)) | ((uint32_t)f2bf(fmaxf(h5, n5)) << 16);
            sm.w = (uint32_t)f2bf(fmaxf(h6, n6)) | ((uint32_t)f2bf(fmaxf(h7, n7)) << 16);
            *reinterpret_cast<uint4*>(mx + (size_t)d * HD + f0) = sm;
        }
    }
}

// ---------------------------------------------------------------- launch

extern "C" void kernel_launch(void* const* d_in, const int* in_sizes, int n_in,
                              void* d_out, int out_size, void* d_ws, size_t ws_size,
                              hipStream_t stream) {
    const float* x        = (const float*)d_in[0];          // [NN][FIN]
    const int*   ei       = (const int*)d_in[1];            // [2][NE]
    const float* ew       = (const float*)d_in[2];          // [NE]
    /* d_in[3] = numNode scalar = NN */
    const float* Wlin     = (const float*)d_in[4];          // [FIN][HD]
    const float* blin     = (const float*)d_in[5];          // [HD]
    const float* Wc       = (const float*)d_in[6];          // [3][HD][HD]
    const float* att_src  = (const float*)d_in[7];          // [3][HD]
    const float* att_dst  = (const float*)d_in[8];          // [3][HD]
    const float* bias_c   = (const float*)d_in[9];          // [3][HD]
    float* out = (float*)d_out;                              // [NN][HD]

    const int* src = ei;
    const int* dst = ei + NE;

    // workspace layout (16B-aligned blocks, ~44 MB)
    char* w = (char*)d_ws;
    ushort* hb      = (ushort*)w;  w += (size_t)NN * HD * 2;   // h residual (bf16)
    signed char* hp8 = (signed char*)w; w += (size_t)NN * HD;  // hp (int8 scaled)
    float*  sig     = (float*)w;   w += (size_t)NN * 4;        // per-row scale
    ushort* mx      = (ushort*)w;  w += (size_t)NN * HD * 2;   // running max (bf16)
    float*  as_     = (float*)w;   w += (size_t)NN * 4;
    float*  ad_     = (float*)w;   w += (size_t)NN * 4;
    int*    row_ptr = (int*)w;     w += (size_t)(NN + 4) * 4;
    unsigned int* cw = (unsigned int*)w; w += (size_t)NE * 4;  // packed col|bf16(ew)
    uint2*  epk     = (uint2*)w;   w += (size_t)NE * 8;
    int*    bhist   = (int*)w;     w += (size_t)NBK * NCHP * 4;
    int*    bbeg    = (int*)w;     w += (size_t)(NBK + 4) * 4;
    ushort* WTh     = (ushort*)w;  w += (size_t)(HD * FIN + 3 * HD * HD) * 2;
    ushort* WTl     = (ushort*)w;  w += (size_t)(HD * FIN + 3 * HD * HD) * 2;
    ushort* WlinTh = WTh,            *WlinTl = WTl;
    ushort* WcTh   = WTh + HD * FIN, *WcTl   = WTl + HD * FIN;

    const int TB = 256;
    const int nblk_w = (NN * 64 + TB - 1) / TB;      // one wave per node
    const int nblk_g = (NN + 127) / 128;             // 391 (128 rows per block)
    const int nsplit = HD * FIN + 3 * HD * HD;       // all weight elements

    // ---- fused weight transpose + split (1 launch) ----
    k_split_all<<<(nsplit + TB - 1) / TB, TB, 0, stream>>>(Wlin, Wc, WTh, WTl);

    // ---- CSR build (atomic-reservation-free binning) ----
    k_bhist<<<NCH, 1024, 0, stream>>>(dst, bhist);
    k_bscan<<<1, 256, 0, stream>>>(bhist, bbeg, row_ptr);
    k_binscatter<<<NCH, 1024, 0, stream>>>(src, dst, ew, bhist, epk);
    k_build<<<NBK, 256, 0, stream>>>(epk, bbeg, row_ptr, cw);

    // ---- input projection: h = x @ Wlin + blin (bf16 out, fp32 A split) ----
    k_gemm_mfma<FIN, false, false, false><<<nblk_g, TB, 0, stream>>>(
        x, nullptr, WlinTh, WlinTl, blin, hb, nullptr, nullptr,
        nullptr, nullptr, nullptr, nullptr, NN);

    // ---- 3 GAT layers (A = h bf16 exact -> 2-MFMA path; hp emitted int8) ----
    for (int layer = 0; layer < 3; ++layer) {
        k_gemm_mfma<HD, true, true, true><<<nblk_g, TB, 0, stream>>>(
            nullptr, hb, WcTh + (size_t)layer * HD * HD, WcTl + (size_t)layer * HD * HD,
            nullptr, nullptr, hp8, sig,
            att_src + layer * HD, att_dst + layer * HD, as_, ad_, NN);
        int mode = (layer == 0) ? 0 : (layer == 2 ? 2 : 1);
        k_agg<<<nblk_w, TB, 0, stream>>>(hp8, sig, hb, as_, ad_, row_ptr, cw,
                                         bias_c + layer * HD, out, mx, mode);
    }
}